// Round 10
// baseline (396.104 us; speedup 1.0000x reference)
//
#include <hip/hip_runtime.h>
#include <hip/hip_cooperative_groups.h>
#include <cstdint>

namespace cg = cooperative_groups;

#define HW 200704      // 448*448
#define IMG_W 448
#define NCLS 20
#define NDIM 256
#define NB 392         // pseudo tiles per batch (512 px each)
#define CAPB 12        // per-(class,tile) candidate slots; mean 5.12 (overflow -> exact fallback)
#define CAPG 2560      // global candidate cap per (b,c); mean 2016
#define TFILT 0.99f
#define LK 260         // padded LDS stride: float4-aligned, 260%32==4
#define GRID 256       // cooperative grid: 1 block/CU

// async global->LDS DMA, 16B per lane, dest = wave-uniform base + lane*16
#define ASYNC_COPY16(gp, lp)                                                   \
  __builtin_amdgcn_global_load_lds(                                            \
      (const __attribute__((address_space(1))) void*)(gp),                     \
      (__attribute__((address_space(3))) void*)(lp), 16, 0, 0)

struct FeatS {
  float sW[784];
  float sPart[4][256];
  float cv[CAPG]; int ci[CAPG];
  float wv[16]; int wi[16];
  float selV; int selI;
  int sTop[25];
  int sN, sFb;
};
struct LossS {
  float sFsm[NCLS * LK], sFc[NCLS * LK], sPw[NCLS * LK];
  float sMat[NCLS * NCLS], sRow[NCLS], sNormI[NCLS], sNormC[NCLS];
  int sZI[NCLS], sZC[NCLS], sQual[NCLS];
  float sPres[2][NCLS];
  float sScal[2];
};

__global__ __launch_bounds__(1024, 4) void k_mega(const float* __restrict__ fmap,
                                                  float* __restrict__ fmapT,
                                                  const float* __restrict__ cam,
                                                  const float* __restrict__ cls_label,
                                                  const float* __restrict__ hig_p,
                                                  const float* __restrict__ low_p,
                                                  const float* __restrict__ bg_p,
                                                  float* __restrict__ W,
                                                  int* __restrict__ counts,
                                                  int* __restrict__ cntBlk,
                                                  int* __restrict__ candIdx,
                                                  const float* __restrict__ proj_w,
                                                  const float* __restrict__ fc_init,
                                                  float* __restrict__ fsm_g,
                                                  float* __restrict__ out) {
  __shared__ union {
    float tile[2][NCLS][512];      // 81920 B: pseudo double buffer
    float ttile[32][33];           // transpose tile (aliases, sequential use)
    FeatS f;
    LossS l;
  } sm;
  __shared__ float sLab[2][NCLS];
  __shared__ int sCnt[2][NCLS];

  cg::grid_group grid = cg::this_grid();
  int tid = threadIdx.x;
  int bid = blockIdx.x;
  int wave = tid >> 6, lane = tid & 63;

  // ================= phase 0: zero W + counts ==============================
  {
    int idx = bid * 1024 + tid;
    if (idx < 31360) W[idx] = 0.0f;
    if (idx >= 31360 && idx < 31400) counts[idx - 31360] = 0;
  }
  grid.sync();

  // ================= phase 1: pseudo (double-buffered) + transpose =========
  if (tid < 40) { sLab[tid / NCLS][tid % NCLS] = cls_label[tid]; }
  if (tid < 40) { ((int*)sCnt)[tid] = 0; }
  float hig = hig_p[0], low = low_p[0], bg = bg_p[0];

  // contiguous tile range per block: 784 tiles over 256 blocks
  int nT = 3 + (bid < 16 ? 1 : 0);
  int t0 = bid * 3 + min(bid, 16);
  int prevB = 0, prevBlk = 0, prevP = 0;

  for (int it = 0; it < nT; ++it) {
    int tt = t0 + it;
    int p = it & 1;
    if (it == 0) {
      // issue tile 0 DMAs
      const float* camb = cam + (size_t)(tt / NB) * NCLS * HW + (tt % NB) * 512;
      for (int d = wave; d < 40; d += 16) {
        int c = d >> 1, h = d & 1;
        ASYNC_COPY16(camb + (size_t)c * HW + h * 256 + lane * 4, &sm.tile[0][c][h * 256]);
      }
    }
    __syncthreads();   // drains tile-it DMAs (issued last iter or above)
    if (it > 0 && tid < NCLS) {
      cntBlk[(prevB * NCLS + tid) * NB + prevBlk] = sCnt[prevP][tid];
      sCnt[prevP][tid] = 0;
    }
    if (it + 1 < nT) {   // issue next tile's DMAs BEFORE consuming current
      int tn = tt + 1;
      const float* camb = cam + (size_t)(tn / NB) * NCLS * HW + (tn % NB) * 512;
      int q = (it + 1) & 1;
      for (int d = wave; d < 40; d += 16) {
        int c = d >> 1, h = d & 1;
        ASYNC_COPY16(camb + (size_t)c * HW + h * 256 + lane * 4, &sm.tile[q][c][h * 256]);
      }
    }
    // ---- consume tile tt (512 px, tid<512) ----
    int b = tt / NB, blkInB = tt % NB;
    if (tid < 512) {
      int pix = blkInB * 512 + tid;
      float top1 = -1.0f, sec = -1.0f;
      int idx1 = 0;
      unsigned cm = 0u;
#pragma unroll
      for (int c = 0; c < NCLS; ++c) {
        float x = sm.tile[p][c][tid] * sLab[b][c];
        // ascending c + strict '>' == lowest-index tie-break (JAX top_k)
        bool gt = x > top1;
        sec = gt ? top1 : fmaxf(sec, fminf(x, top1));
        idx1 = gt ? c : idx1;
        top1 = gt ? x : top1;
        cm |= (x >= TFILT) ? (1u << c) : 0u;
      }
      unsigned m = cm;
      while (m) {
        int c = __builtin_ctz(m); m &= m - 1u;
        int pos = atomicAdd(&sCnt[p][c], 1);
        if (pos < CAPB)
          candIdx[(size_t)((b * NCLS + c) * NB + blkInB) * CAPB + pos] = pix;
      }
      int ps = idx1 + 1;
      if (top1 < hig) ps = 255;
      if (top1 < low) ps = 0;
      if (top1 < bg)  ps = 0;
      if ((top1 - sec < 0.3f) && (top1 > hig)) ps = 255;
      if (ps >= 1 && ps <= NCLS) {
        int cls = ps - 1;
        int y = pix / IMG_W, x = pix % IMG_W;
        float sy = (y + 0.5f) * 0.0625f - 0.5f; sy = fminf(fmaxf(sy, 0.0f), 27.0f);
        float sx = (x + 0.5f) * 0.0625f - 0.5f; sx = fminf(fmaxf(sx, 0.0f), 27.0f);
        int fy0 = (int)sy, fx0 = (int)sx;
        int fy1 = min(fy0 + 1, 27), fx1 = min(fx0 + 1, 27);
        float wy = sy - (float)fy0, wx = sx - (float)fx0;
        float* Wb = W + (size_t)(b * NCLS + cls) * 784;
        atomicAdd(&Wb[fy0 * 28 + fx0], (1.0f - wy) * (1.0f - wx));
        atomicAdd(&Wb[fy0 * 28 + fx1], (1.0f - wy) * wx);
        atomicAdd(&Wb[fy1 * 28 + fx0], wy * (1.0f - wx));
        atomicAdd(&Wb[fy1 * 28 + fx1], wy * wx);
        atomicAdd(&counts[b * NCLS + cls], 1);
      }
    }
    prevB = b; prevBlk = blkInB; prevP = p;
  }
  __syncthreads();
  if (tid < NCLS)
    cntBlk[(prevB * NCLS + tid) * NB + prevBlk] = sCnt[prevP][tid];
  __syncthreads();

  // ---- transpose: fmap [B,256,784] -> fmapT [B,784,256] (400 tiles) ----
  for (int blk = bid; blk < 400; blk += GRID) {
    int b = blk / 200;
    int t = blk % 200;
    int dT = t / 25, sT2 = t % 25;
    int ty = tid >> 5, tx = tid & 31;   // 32x32, 1 elem/thread
    {
      int d = dT * 32 + ty;
      int s = sT2 * 32 + tx;
      if (s < 784) sm.ttile[ty][tx] = fmap[((size_t)(b * 256 + d)) * 784 + s];
    }
    __syncthreads();
    {
      int s = sT2 * 32 + ty;
      int d = dT * 32 + tx;
      if (s < 784) fmapT[((size_t)(b * 784 + s)) * 256 + d] = sm.ttile[tx][ty];
    }
    __syncthreads();
  }
  __threadfence();
  grid.sync();

  // ================= phase 2: features (blocks 0..39) ======================
  if (bid < 40) {
    int bc = bid;
    int b = bc / NCLS;
    int dim = tid & 255, part = tid >> 8;
    bool present = (cls_label[bc] != 0.0f);
    int cnt = counts[bc];
    const float* fT = fmapT + (size_t)b * 784 * 256;
    float res = 0.0f;
    if (present) {
      if (cnt > 0) {
        for (int s = tid; s < 784; s += 1024) sm.f.sW[s] = W[(size_t)bc * 784 + s];
        __syncthreads();
        float a0 = 0.0f, a1 = 0.0f, a2 = 0.0f, a3 = 0.0f;
        int s0 = part * 196;
        for (int s = s0; s < s0 + 196; s += 4) {
          a0 += sm.f.sW[s]     * fT[(size_t)(s)     * 256 + dim];
          a1 += sm.f.sW[s + 1] * fT[(size_t)(s + 1) * 256 + dim];
          a2 += sm.f.sW[s + 2] * fT[(size_t)(s + 2) * 256 + dim];
          a3 += sm.f.sW[s + 3] * fT[(size_t)(s + 3) * 256 + dim];
        }
        sm.f.sPart[part][dim] = (a0 + a1) + (a2 + a3);
        __syncthreads();
        if (tid < 256)
          res = ((sm.f.sPart[0][tid] + sm.f.sPart[1][tid]) +
                 (sm.f.sPart[2][tid] + sm.f.sPart[3][tid])) / fmaxf((float)cnt, 1.0f);
      } else {
        // ---- exact top-25 (JAX tie-break) from per-tile candidate lists ----
        if (tid == 0) { sm.f.sN = 0; sm.f.sFb = 0; }
        __syncthreads();
        const float* camc = cam + (size_t)bc * HW;   // lab==1 -> valid_cam == cam
        if (tid < NB) {
          int cb = cntBlk[(size_t)bc * NB + tid];
          if (cb > CAPB) sm.f.sFb = 1;
          else if (cb > 0) {
            int base = atomicAdd(&sm.f.sN, cb);
            for (int j = 0; j < cb; ++j) {
              int pp = base + j;
              if (pp < CAPG) sm.f.ci[pp] = candIdx[(size_t)((size_t)bc * NB + tid) * CAPB + j];
            }
          }
        }
        __syncthreads();
        int n = sm.f.sN;
        bool fb = sm.f.sFb || (n < 25) || (n > CAPG);
        if (!fb) for (int pp = tid; pp < n; pp += 1024) sm.f.cv[pp] = camc[sm.f.ci[pp]];
        __syncthreads();
        float lastV = 3.0e38f; int lastI = -1;
        for (int r = 0; r < 25; ++r) {
          float bv = -1.0e30f; int bi = 0x7fffffff;
          if (!fb) {
            for (int pp = tid; pp < n; pp += 1024) {
              float vv2 = sm.f.cv[pp]; int ii = sm.f.ci[pp];
              if (((vv2 < lastV) || (vv2 == lastV && ii > lastI)) &&
                  ((vv2 > bv) || (vv2 == bv && ii < bi))) { bv = vv2; bi = ii; }
            }
          } else {
            for (int pp = tid; pp < HW; pp += 1024) {
              float vv2 = camc[pp];
              if (((vv2 < lastV) || (vv2 == lastV && pp > lastI)) &&
                  ((vv2 > bv) || (vv2 == bv && pp < bi))) { bv = vv2; bi = pp; }
            }
          }
          for (int off = 32; off > 0; off >>= 1) {
            float ov = __shfl_xor(bv, off, 64);
            int   oi = __shfl_xor(bi, off, 64);
            if (ov > bv || (ov == bv && oi < bi)) { bv = ov; bi = oi; }
          }
          if ((tid & 63) == 0) { sm.f.wv[tid >> 6] = bv; sm.f.wi[tid >> 6] = bi; }
          __syncthreads();
          if (tid == 0) {
            for (int w = 1; w < 16; ++w)
              if (sm.f.wv[w] > bv || (sm.f.wv[w] == bv && sm.f.wi[w] < bi)) { bv = sm.f.wv[w]; bi = sm.f.wi[w]; }
            sm.f.selV = bv; sm.f.selI = bi; sm.f.sTop[r] = bi;
          }
          __syncthreads();
          lastV = sm.f.selV; lastI = sm.f.selI;
        }
        float at = 0.0f;
        for (int r = part; r < 25; r += 4) {
          int pp = sm.f.sTop[r];
          int y = pp / IMG_W, x = pp % IMG_W;
          float sy = (y + 0.5f) * 0.0625f - 0.5f; sy = fminf(fmaxf(sy, 0.0f), 27.0f);
          float sx = (x + 0.5f) * 0.0625f - 0.5f; sx = fminf(fmaxf(sx, 0.0f), 27.0f);
          int fy0 = (int)sy, fx0 = (int)sx;
          int fy1 = min(fy0 + 1, 27), fx1 = min(fx0 + 1, 27);
          float wy = sy - (float)fy0, wx = sx - (float)fx0;
          at += (1.0f - wy) * (1.0f - wx) * fT[(size_t)(fy0 * 28 + fx0) * 256 + dim]
              + (1.0f - wy) * wx          * fT[(size_t)(fy0 * 28 + fx1) * 256 + dim]
              + wy          * (1.0f - wx) * fT[(size_t)(fy1 * 28 + fx0) * 256 + dim]
              + wy          * wx          * fT[(size_t)(fy1 * 28 + fx1) * 256 + dim];
        }
        sm.f.sPart[part][dim] = at;
        __syncthreads();
        if (tid < 256)
          res = ((sm.f.sPart[0][tid] + sm.f.sPart[1][tid]) +
                 (sm.f.sPart[2][tid] + sm.f.sPart[3][tid])) * (1.0f / 25.0f);
      }
    }
    if (tid < 256) fsm_g[(size_t)bc * 256 + tid] = res;
  }
  __threadfence();
  grid.sync();

  // ================= phase 3: loss (block 0) ===============================
  if (bid != 0) return;
  for (int idx = tid; idx < NCLS * NDIM; idx += 1024) {
    int r = idx >> 8, d = idx & 255;
    sm.l.sFc[r * LK + d] = fc_init[idx];
    sm.l.sPw[r * LK + d] = proj_w[idx];
  }
  if (tid < 40) sm.l.sPres[tid / NCLS][tid % NCLS] = cls_label[tid];
  if (tid == 0) { sm.l.sScal[0] = 0.0f; sm.l.sScal[1] = 0.0f; }
  __syncthreads();

  for (int bb = 0; bb < 2; ++bb) {
    for (int idx = tid; idx < NCLS * NDIM; idx += 1024)
      sm.l.sFsm[(idx >> 8) * LK + (idx & 255)] = fsm_g[bb * NCLS * NDIM + idx];
    __syncthreads();
    {
      int g = tid >> 3, sub = tid & 7;
      if (g < 40) {
        const float* row = (g < NCLS) ? &sm.l.sFsm[g * LK] : &sm.l.sFc[(g - NCLS) * LK];
        float a0 = 0.0f, a1 = 0.0f, a2 = 0.0f, a3 = 0.0f;
        int d0 = sub * 32;
#pragma unroll
        for (int d = d0; d < d0 + 32; d += 8) {
          float4 x = *(const float4*)&row[d];
          float4 y = *(const float4*)&row[d + 4];
          a0 += x.x * x.x + x.y * x.y;
          a1 += x.z * x.z + x.w * x.w;
          a2 += y.x * y.x + y.y * y.y;
          a3 += y.z * y.z + y.w * y.w;
        }
        float s = (a0 + a1) + (a2 + a3);
        s += __shfl_xor(s, 1, 64);
        s += __shfl_xor(s, 2, 64);
        s += __shfl_xor(s, 4, 64);
        if (sub == 0) {
          if (g < NCLS) { sm.l.sNormI[g] = fmaxf(sqrtf(s), 1e-12f); sm.l.sZI[g] = (s == 0.0f); }
          else { sm.l.sNormC[g - NCLS] = fmaxf(sqrtf(s), 1e-12f); sm.l.sZC[g - NCLS] = (s == 0.0f); }
        }
      }
    }
    __syncthreads();
    {
      int pair = tid >> 1, sub = tid & 1;
      if (pair < 400) {
        int i = pair / NCLS, j = pair % NCLS;
        float c0;
        if (sm.l.sZI[i] || sm.l.sZC[j]) c0 = 0.0f;
        else {
          const float* ra = &sm.l.sFsm[i * LK];
          const float* rb = &sm.l.sFc[j * LK];
          float a0 = 0.0f, a1 = 0.0f, a2 = 0.0f, a3 = 0.0f;
          int d0 = sub * 128;
          for (int d = d0; d < d0 + 128; d += 8) {
            float4 x  = *(const float4*)&ra[d];
            float4 y  = *(const float4*)&rb[d];
            float4 x2 = *(const float4*)&ra[d + 4];
            float4 y2 = *(const float4*)&rb[d + 4];
            a0 += x.x * y.x + x.y * y.y;
            a1 += x.z * y.z + x.w * y.w;
            a2 += x2.x * y2.x + x2.y * y2.y;
            a3 += x2.z * y2.z + x2.w * y2.w;
          }
          float acc = (a0 + a1) + (a2 + a3);
          acc += __shfl_xor(acc, 1, 64);
          c0 = fabsf(acc / (sm.l.sNormI[i] * sm.l.sNormC[j]));
        }
        if (sub == 0) sm.l.sMat[pair] = fminf(fmaxf(c0, 1e-5f), 1.0f - 1e-5f);
      }
    }
    __syncthreads();
    {
      int i = tid >> 5, jj = tid & 31;
      if (i < NCLS) {
        float pres = (sm.l.sPres[bb][i] > 0.5f) ? 1.0f : 0.0f;
        float contrib = 0.0f, omv = -3.0e38f;
        if (jj < NCLS) {
          float c0 = sm.l.sMat[i * NCLS + jj];
          float ident = (jj == i) ? pres : 0.0f;
          contrib = ident * logf(c0) + (1.0f - ident) * log1pf(-c0);
          if (jj != i) omv = c0;
        }
#pragma unroll
        for (int off = 1; off < 32; off <<= 1) {
          contrib += __shfl_xor(contrib, off, 64);
          omv = fmaxf(omv, __shfl_xor(omv, off, 64));
        }
        if (jj == 0) { sm.l.sRow[i] = contrib; sm.l.sQual[i] = (pres > 0.5f && omv < 0.6f) ? 1 : 0; }
      }
    }
    __syncthreads();
    if (tid == 0) {
      float s = 0.0f;
      for (int r = 0; r < NCLS; ++r) s += sm.l.sRow[r];
      sm.l.sScal[0] -= s / 400.0f;
    }
    __syncthreads();
    {
      int pair = tid >> 1, sub = tid & 1;
      if (pair < 400) {
        int i = pair / NCLS, j = pair % NCLS;
        float acc = 0.0f;
        if (!sm.l.sZI[i]) {
          const float* ra = &sm.l.sFsm[i * LK];
          const float* rb = &sm.l.sPw[j * LK];
          float a0 = 0.0f, a1 = 0.0f, a2 = 0.0f, a3 = 0.0f;
          int d0 = sub * 128;
          for (int d = d0; d < d0 + 128; d += 8) {
            float4 x  = *(const float4*)&ra[d];
            float4 y  = *(const float4*)&rb[d];
            float4 x2 = *(const float4*)&ra[d + 4];
            float4 y2 = *(const float4*)&rb[d + 4];
            a0 += x.x * y.x + x.y * y.y;
            a1 += x.z * y.z + x.w * y.w;
            a2 += x2.x * y2.x + x2.y * y2.y;
            a3 += x2.z * y2.z + x2.w * y2.w;
          }
          acc = (a0 + a1) + (a2 + a3);
          acc += __shfl_xor(acc, 1, 64);
        }
        if (sub == 0) sm.l.sMat[pair] = acc;
      }
    }
    __syncthreads();
    {
      int i = tid >> 5, jj = tid & 31;
      if (i < NCLS) {
        float l = (jj < NCLS) ? sm.l.sMat[i * NCLS + jj] : -3.0e38f;
        float m = l;
#pragma unroll
        for (int off = 1; off < 32; off <<= 1) m = fmaxf(m, __shfl_xor(m, off, 64));
        float e = (jj < NCLS) ? expf(l - m) : 0.0f;
        float S = e;
#pragma unroll
        for (int off = 1; off < 32; off <<= 1) S += __shfl_xor(S, off, 64);
        float term = 0.0f;
        if (jj < NCLS) {
          float p = e / S;
          term = (jj == i) ? fmaxf(logf(p), -100.0f) : fmaxf(log1pf(-p), -100.0f);
        }
#pragma unroll
        for (int off = 1; off < 32; off <<= 1) term += __shfl_xor(term, off, 64);
        if (jj == 0) sm.l.sRow[i] = -term / 20.0f;
      }
    }
    __syncthreads();
    if (tid == 0) {
      float add = 0.0f; int nq = 0;
      for (int r = 0; r < NCLS; ++r) if (sm.l.sQual[r]) { add += sm.l.sRow[r]; nq++; }
      float lc = sm.l.sScal[1] + add;
      if (nq > 0) lc = lc / fmaxf((float)nq, 1.0f);
      sm.l.sScal[1] = lc;
    }
    for (int idx = tid; idx < NCLS * NDIM; idx += 1024) {
      int r = idx >> 8, d = idx & 255;
      if (sm.l.sQual[r])
        sm.l.sFc[r * LK + d] = 0.95f * sm.l.sFc[r * LK + d] + 0.05f * sm.l.sFsm[r * LK + d];
    }
    __syncthreads();
  }
  if (tid == 0) out[0] = sm.l.sScal[0] + sm.l.sScal[1];
}

// ---------------------------------------------------------------------------
extern "C" void kernel_launch(void* const* d_in, const int* in_sizes, int n_in,
                              void* d_out, int out_size, void* d_ws, size_t ws_size,
                              hipStream_t stream) {
  const float* fmap      = (const float*)d_in[0];
  const float* cam       = (const float*)d_in[1];
  const float* cls_label = (const float*)d_in[2];
  const float* proj_w    = (const float*)d_in[3];
  const float* fc_init   = (const float*)d_in[4];
  const float* hig       = (const float*)d_in[5];
  const float* low       = (const float*)d_in[6];
  const float* bg        = (const float*)d_in[7];
  float* out = (float*)d_out;

  char* ws = (char*)d_ws;
  float* W       = (float*)(ws);                 // 125440 B
  int*   counts  = (int*)  (ws + 125440);        // 160 B
  int*   cntBlk  = (int*)  (ws + 125600);        // 40*392*4 = 62720 B
  int*   candIdx = (int*)  (ws + 188320);        // 40*392*12*4 = 752640 B
  float* fsm     = (float*)(ws + 940960);        // 40960 B
  float* fmapT   = (float*)(ws + 981920);        // 1605632 B

  void* args[] = {(void*)&fmap, (void*)&fmapT, (void*)&cam, (void*)&cls_label,
                  (void*)&hig, (void*)&low, (void*)&bg, (void*)&W, (void*)&counts,
                  (void*)&cntBlk, (void*)&candIdx, (void*)&proj_w, (void*)&fc_init,
                  (void*)&fsm, (void*)&out};
  hipLaunchCooperativeKernel((void*)k_mega, dim3(GRID), dim3(1024), args, 0, stream);
}

// Round 11
// 178.980 us; speedup vs baseline: 2.2131x; 2.2131x over previous
//
#include <hip/hip_runtime.h>
#include <cstdint>

#define HW 200704      // 448*448
#define IMG_W 448
#define NCLS 20
#define NDIM 256
#define NB2 784        // cam tiles per batch (256 px each)
#define TFILT 0.99f
#define LK 260         // padded LDS stride: float4-aligned
#define HWCHUNK 196    // HW/1024

// async global->LDS DMA, 16B per lane, dest = wave-uniform base + lane*16
#define ASYNC_COPY16(gp, lp)                                                   \
  __builtin_amdgcn_global_load_lds(                                            \
      (const __attribute__((address_space(1))) void*)(gp),                     \
      (__attribute__((address_space(3))) void*)(lp), 16, 0, 0)

// ---------------------------------------------------------------------------
// K1: fused [pseudo | transpose]. Pseudo stages ONLY present classes (~half),
// consume is pure top-2 (no candidate side effects — top-25 moved to k_feat's
// exact full-scan, which statistically never runs since counts ~ thousands).
__global__ __launch_bounds__(256) void k_front(const float* __restrict__ fmap,
                                               float* __restrict__ fmapT,
                                               const float* __restrict__ cam,
                                               const float* __restrict__ cls_label,
                                               const float* __restrict__ hig_p,
                                               const float* __restrict__ low_p,
                                               const float* __restrict__ bg_p,
                                               float* __restrict__ W,
                                               int* __restrict__ counts) {
  __shared__ float sT[NCLS][256];      // 20 KB tile (rows 0..np-1 used)
  __shared__ int presList[NCLS];
  __shared__ int sNP;
  int tid = threadIdx.x;

  if (blockIdx.x >= 2 * NB2) {
    // ---------------- transpose part: fmap [B,256,784] -> fmapT [B,784,256]
    float (*tile)[33] = (float (*)[33]) & sT[0][0];
    int blk = blockIdx.x - 2 * NB2;
    int b = blk / 200;
    int t = blk % 200;
    int dT = t / 25, sT2 = t % 25;
    int ty = tid >> 5, tx = tid & 31;
#pragma unroll
    for (int r = 0; r < 4; ++r) {
      int d = dT * 32 + ty + r * 8;
      int s = sT2 * 32 + tx;
      if (s < 784) tile[ty + r * 8][tx] = fmap[((size_t)(b * 256 + d)) * 784 + s];
    }
    __syncthreads();
#pragma unroll
    for (int r = 0; r < 4; ++r) {
      int s = sT2 * 32 + ty + r * 8;
      int d = dT * 32 + tx;
      if (s < 784) fmapT[((size_t)(b * 784 + s)) * 256 + d] = tile[tx][ty + r * 8];
    }
    return;
  }

  // ---------------- pseudo part
  int b = blockIdx.x / NB2;
  int blkInB = blockIdx.x % NB2;
  int pix0 = blkInB * 256;
  int wave = tid >> 6, lane = tid & 63;

  // present-class list via wave ballot
  if (tid < 64) {
    bool pres = (tid < NCLS) && (cls_label[b * NCLS + tid] != 0.0f);
    unsigned long long pm = __ballot(pres);
    if (pres) presList[(int)__popcll(pm & ((1ull << tid) - 1ull))] = tid;
    if (tid == 0) sNP = (int)__popcll(pm);
  }
  __syncthreads();
  int np = sNP;
  const float* camb = cam + (size_t)b * NCLS * HW + pix0;

  // ---- stage: one 1KB DMA per present class ----
  for (int k = wave; k < np; k += 4)
    ASYNC_COPY16(camb + (size_t)presList[k] * HW + lane * 4, &sT[k][0]);
  __syncthreads();                                  // drains vmcnt before ds_read

  // ---- consume: pure branchless top-2 (1 px/thread) ----
  // ascending presList + strict '>' == lowest-index tie-break among present;
  // absent classes contribute only exact 0s -> folded below (proven r2).
  float top1 = -1.0f, sec = -1.0f;
  int cls1 = 0;
  for (int k = 0; k < np; ++k) {
    float x = sT[k][tid];                           // lab==1 for present
    bool gt = x > top1;
    sec = gt ? top1 : fmaxf(sec, fminf(x, top1));
    cls1 = gt ? presList[k] : cls1;
    top1 = gt ? x : top1;
  }
  if (np < NCLS) sec = fmaxf(sec, 0.0f);            // absent-class fold
  float hig = hig_p[0], low = low_p[0], bg = bg_p[0];
  int pix = pix0 + tid;
  int ps = cls1 + 1;
  if (top1 < hig) ps = 255;
  if (top1 < low) ps = 0;
  if (top1 < bg)  ps = 0;
  if ((top1 - sec < 0.3f) && (top1 > hig)) ps = 255;
  if (ps >= 1 && ps <= NCLS) {
    int cls = ps - 1;
    int y = pix / IMG_W, x = pix % IMG_W;
    float sy = (y + 0.5f) * 0.0625f - 0.5f; sy = fminf(fmaxf(sy, 0.0f), 27.0f);
    float sx = (x + 0.5f) * 0.0625f - 0.5f; sx = fminf(fmaxf(sx, 0.0f), 27.0f);
    int fy0 = (int)sy, fx0 = (int)sx;
    int fy1 = min(fy0 + 1, 27), fx1 = min(fx0 + 1, 27);
    float wy = sy - (float)fy0, wx = sx - (float)fx0;
    float* Wb = W + (size_t)(b * NCLS + cls) * 784;
    atomicAdd(&Wb[fy0 * 28 + fx0], (1.0f - wy) * (1.0f - wx));   // no return: pipelined
    atomicAdd(&Wb[fy0 * 28 + fx1], (1.0f - wy) * wx);
    atomicAdd(&Wb[fy1 * 28 + fx0], wy * (1.0f - wx));
    atomicAdd(&Wb[fy1 * 28 + fx1], wy * wx);
    atomicAdd(&counts[b * NCLS + cls], 1);
  }
}

// ---------------------------------------------------------------------------
// K2: fused features + loss. 40 blocks x 1024 threads; last-block ticket runs
// the ILP-parallel loss (bit-identical math to r7-r9). cnt==0 present classes
// (statistically never) use the exact full-scan top-25 tournament.
__global__ __launch_bounds__(1024) void k_feat_loss(const float* __restrict__ fmapT,
                                                    const float* __restrict__ cam,
                                                    const float* __restrict__ Wg,
                                                    const int* __restrict__ counts,
                                                    const float* __restrict__ cls_label,
                                                    const float* __restrict__ proj_w,
                                                    const float* __restrict__ fc_init,
                                                    int* __restrict__ done,
                                                    float* __restrict__ fsm_g,
                                                    float* __restrict__ out) {
  __shared__ float sW[784];
  __shared__ float sPart[4][256];
  __shared__ float wv[16]; __shared__ int wi[16];
  __shared__ float selV; __shared__ int selI;
  __shared__ int sTop[25];
  __shared__ int sLast;
  // loss state
  __shared__ float sFsm[NCLS * LK], sFc[NCLS * LK], sPw[NCLS * LK];
  __shared__ float sMat[NCLS * NCLS], sRow[NCLS], sNormI[NCLS], sNormC[NCLS];
  __shared__ int   sZI[NCLS], sZC[NCLS], sQual[NCLS];
  __shared__ float sPres[2][NCLS];
  __shared__ float sScal[2];

  int bc = blockIdx.x;
  int b = bc / NCLS;
  int tid = threadIdx.x;
  int dim = tid & 255, part = tid >> 8;
  bool present = (cls_label[bc] != 0.0f);
  int cnt = counts[bc];
  const float* fT = fmapT + (size_t)b * 784 * 256;
  float res = 0.0f;

  if (present) {
    if (cnt > 0) {
      for (int s = tid; s < 784; s += 1024) sW[s] = Wg[(size_t)bc * 784 + s];
      __syncthreads();
      float a0 = 0.0f, a1 = 0.0f, a2 = 0.0f, a3 = 0.0f;
      int s0 = part * 196;
      for (int s = s0; s < s0 + 196; s += 4) {
        a0 += sW[s]     * fT[(size_t)(s)     * 256 + dim];
        a1 += sW[s + 1] * fT[(size_t)(s + 1) * 256 + dim];
        a2 += sW[s + 2] * fT[(size_t)(s + 2) * 256 + dim];
        a3 += sW[s + 3] * fT[(size_t)(s + 3) * 256 + dim];
      }
      sPart[part][dim] = (a0 + a1) + (a2 + a3);
      __syncthreads();
      if (tid < 256)
        res = ((sPart[0][tid] + sPart[1][tid]) + (sPart[2][tid] + sPart[3][tid]))
              / fmaxf((float)cnt, 1.0f);
    } else {
      // ---- exact top-25 (JAX tie-break) by full scan; ~never taken ----
      const float* camc = cam + (size_t)bc * HW;   // lab==1 -> valid_cam == cam
      float lastV = 3.0e38f; int lastI = -1;
      for (int r = 0; r < 25; ++r) {
        float bv = -1.0e30f; int bi = 0x7fffffff;
        for (int p = tid; p < HW; p += 1024) {
          float vv2 = camc[p];
          if (((vv2 < lastV) || (vv2 == lastV && p > lastI)) &&
              ((vv2 > bv) || (vv2 == bv && p < bi))) { bv = vv2; bi = p; }
        }
        for (int off = 32; off > 0; off >>= 1) {
          float ov = __shfl_xor(bv, off, 64);
          int   oi = __shfl_xor(bi, off, 64);
          if (ov > bv || (ov == bv && oi < bi)) { bv = ov; bi = oi; }
        }
        if ((tid & 63) == 0) { wv[tid >> 6] = bv; wi[tid >> 6] = bi; }
        __syncthreads();
        if (tid == 0) {
          for (int w = 1; w < 16; ++w)
            if (wv[w] > bv || (wv[w] == bv && wi[w] < bi)) { bv = wv[w]; bi = wi[w]; }
          selV = bv; selI = bi; sTop[r] = bi;
        }
        __syncthreads();
        lastV = selV; lastI = selI;
      }
      float at = 0.0f;
      for (int r = part; r < 25; r += 4) {
        int p = sTop[r];
        int y = p / IMG_W, x = p % IMG_W;
        float sy = (y + 0.5f) * 0.0625f - 0.5f; sy = fminf(fmaxf(sy, 0.0f), 27.0f);
        float sx = (x + 0.5f) * 0.0625f - 0.5f; sx = fminf(fmaxf(sx, 0.0f), 27.0f);
        int fy0 = (int)sy, fx0 = (int)sx;
        int fy1 = min(fy0 + 1, 27), fx1 = min(fx0 + 1, 27);
        float wy = sy - (float)fy0, wx = sx - (float)fx0;
        at += (1.0f - wy) * (1.0f - wx) * fT[(size_t)(fy0 * 28 + fx0) * 256 + dim]
            + (1.0f - wy) * wx          * fT[(size_t)(fy0 * 28 + fx1) * 256 + dim]
            + wy          * (1.0f - wx) * fT[(size_t)(fy1 * 28 + fx0) * 256 + dim]
            + wy          * wx          * fT[(size_t)(fy1 * 28 + fx1) * 256 + dim];
      }
      sPart[part][dim] = at;
      __syncthreads();
      if (tid < 256)
        res = ((sPart[0][tid] + sPart[1][tid]) + (sPart[2][tid] + sPart[3][tid])) * (1.0f / 25.0f);
    }
  }
  if (tid < 256) fsm_g[(size_t)bc * 256 + tid] = res;
  __syncthreads();
  // ---- last-block ticket ----
  if (tid == 0) {
    __threadfence();
    int t = atomicAdd(done, 1);
    sLast = (t == 39) ? 1 : 0;
  }
  __syncthreads();
  if (!sLast) return;
  __threadfence();

  // ================= loss (identical math) =================================
  for (int idx = tid; idx < NCLS * NDIM; idx += 1024) {
    int r = idx >> 8, d = idx & 255;
    sFc[r * LK + d] = fc_init[idx];
    sPw[r * LK + d] = proj_w[idx];
  }
  if (tid < 40) sPres[tid / NCLS][tid % NCLS] = cls_label[tid];
  if (tid == 0) { sScal[0] = 0.0f; sScal[1] = 0.0f; }
  __syncthreads();

  for (int bb = 0; bb < 2; ++bb) {
    for (int idx = tid; idx < NCLS * NDIM; idx += 1024)
      sFsm[(idx >> 8) * LK + (idx & 255)] = fsm_g[bb * NCLS * NDIM + idx];
    __syncthreads();
    {
      int g = tid >> 3, sub = tid & 7;
      if (g < 40) {
        const float* row = (g < NCLS) ? &sFsm[g * LK] : &sFc[(g - NCLS) * LK];
        float a0 = 0.0f, a1 = 0.0f, a2 = 0.0f, a3 = 0.0f;
        int d0 = sub * 32;
#pragma unroll
        for (int d = d0; d < d0 + 32; d += 8) {
          float4 x = *(const float4*)&row[d];
          float4 y = *(const float4*)&row[d + 4];
          a0 += x.x * x.x + x.y * x.y;
          a1 += x.z * x.z + x.w * x.w;
          a2 += y.x * y.x + y.y * y.y;
          a3 += y.z * y.z + y.w * y.w;
        }
        float s = (a0 + a1) + (a2 + a3);
        s += __shfl_xor(s, 1, 64);
        s += __shfl_xor(s, 2, 64);
        s += __shfl_xor(s, 4, 64);
        if (sub == 0) {
          if (g < NCLS) { sNormI[g] = fmaxf(sqrtf(s), 1e-12f); sZI[g] = (s == 0.0f); }
          else { sNormC[g - NCLS] = fmaxf(sqrtf(s), 1e-12f); sZC[g - NCLS] = (s == 0.0f); }
        }
      }
    }
    __syncthreads();
    {
      int pair = tid >> 1, sub = tid & 1;
      if (pair < 400) {
        int i = pair / NCLS, j = pair % NCLS;
        float c0;
        if (sZI[i] || sZC[j]) c0 = 0.0f;
        else {
          const float* ra = &sFsm[i * LK];
          const float* rb = &sFc[j * LK];
          float a0 = 0.0f, a1 = 0.0f, a2 = 0.0f, a3 = 0.0f;
          int d0 = sub * 128;
          for (int d = d0; d < d0 + 128; d += 8) {
            float4 x  = *(const float4*)&ra[d];
            float4 y  = *(const float4*)&rb[d];
            float4 x2 = *(const float4*)&ra[d + 4];
            float4 y2 = *(const float4*)&rb[d + 4];
            a0 += x.x * y.x + x.y * y.y;
            a1 += x.z * y.z + x.w * y.w;
            a2 += x2.x * y2.x + x2.y * y2.y;
            a3 += x2.z * y2.z + x2.w * y2.w;
          }
          float acc = (a0 + a1) + (a2 + a3);
          acc += __shfl_xor(acc, 1, 64);
          c0 = fabsf(acc / (sNormI[i] * sNormC[j]));
        }
        if (sub == 0) sMat[pair] = fminf(fmaxf(c0, 1e-5f), 1.0f - 1e-5f);
      }
    }
    __syncthreads();
    {
      int i = tid >> 5, jj = tid & 31;
      if (i < NCLS) {
        float pres = (sPres[bb][i] > 0.5f) ? 1.0f : 0.0f;
        float contrib = 0.0f, omv = -3.0e38f;
        if (jj < NCLS) {
          float c0 = sMat[i * NCLS + jj];
          float ident = (jj == i) ? pres : 0.0f;
          contrib = ident * logf(c0) + (1.0f - ident) * log1pf(-c0);
          if (jj != i) omv = c0;
        }
#pragma unroll
        for (int off = 1; off < 32; off <<= 1) {
          contrib += __shfl_xor(contrib, off, 64);
          omv = fmaxf(omv, __shfl_xor(omv, off, 64));
        }
        if (jj == 0) { sRow[i] = contrib; sQual[i] = (pres > 0.5f && omv < 0.6f) ? 1 : 0; }
      }
    }
    __syncthreads();
    if (tid == 0) {
      float s = 0.0f;
      for (int r = 0; r < NCLS; ++r) s += sRow[r];
      sScal[0] -= s / 400.0f;
    }
    __syncthreads();
    {
      int pair = tid >> 1, sub = tid & 1;
      if (pair < 400) {
        int i = pair / NCLS, j = pair % NCLS;
        float acc = 0.0f;
        if (!sZI[i]) {
          const float* ra = &sFsm[i * LK];
          const float* rb = &sPw[j * LK];
          float a0 = 0.0f, a1 = 0.0f, a2 = 0.0f, a3 = 0.0f;
          int d0 = sub * 128;
          for (int d = d0; d < d0 + 128; d += 8) {
            float4 x  = *(const float4*)&ra[d];
            float4 y  = *(const float4*)&rb[d];
            float4 x2 = *(const float4*)&ra[d + 4];
            float4 y2 = *(const float4*)&rb[d + 4];
            a0 += x.x * y.x + x.y * y.y;
            a1 += x.z * y.z + x.w * y.w;
            a2 += x2.x * y2.x + x2.y * y2.y;
            a3 += x2.z * y2.z + x2.w * y2.w;
          }
          acc = (a0 + a1) + (a2 + a3);
          acc += __shfl_xor(acc, 1, 64);
        }
        if (sub == 0) sMat[pair] = acc;
      }
    }
    __syncthreads();
    {
      int i = tid >> 5, jj = tid & 31;
      if (i < NCLS) {
        float l = (jj < NCLS) ? sMat[i * NCLS + jj] : -3.0e38f;
        float m = l;
#pragma unroll
        for (int off = 1; off < 32; off <<= 1) m = fmaxf(m, __shfl_xor(m, off, 64));
        float e = (jj < NCLS) ? expf(l - m) : 0.0f;
        float S = e;
#pragma unroll
        for (int off = 1; off < 32; off <<= 1) S += __shfl_xor(S, off, 64);
        float term = 0.0f;
        if (jj < NCLS) {
          float p = e / S;
          term = (jj == i) ? fmaxf(logf(p), -100.0f) : fmaxf(log1pf(-p), -100.0f);
        }
#pragma unroll
        for (int off = 1; off < 32; off <<= 1) term += __shfl_xor(term, off, 64);
        if (jj == 0) sRow[i] = -term / 20.0f;
      }
    }
    __syncthreads();
    if (tid == 0) {
      float add = 0.0f; int nq = 0;
      for (int r = 0; r < NCLS; ++r) if (sQual[r]) { add += sRow[r]; nq++; }
      float lc = sScal[1] + add;
      if (nq > 0) lc = lc / fmaxf((float)nq, 1.0f);
      sScal[1] = lc;
    }
    for (int idx = tid; idx < NCLS * NDIM; idx += 1024) {
      int r = idx >> 8, d = idx & 255;
      if (sQual[r]) sFc[r * LK + d] = 0.95f * sFc[r * LK + d] + 0.05f * sFsm[r * LK + d];
    }
    __syncthreads();
  }
  if (tid == 0) out[0] = sScal[0] + sScal[1];
}

// ---------------------------------------------------------------------------
extern "C" void kernel_launch(void* const* d_in, const int* in_sizes, int n_in,
                              void* d_out, int out_size, void* d_ws, size_t ws_size,
                              hipStream_t stream) {
  const float* fmap      = (const float*)d_in[0];
  const float* cam       = (const float*)d_in[1];
  const float* cls_label = (const float*)d_in[2];
  const float* proj_w    = (const float*)d_in[3];
  const float* fc_init   = (const float*)d_in[4];
  const float* hig       = (const float*)d_in[5];
  const float* low       = (const float*)d_in[6];
  const float* bg        = (const float*)d_in[7];
  float* out = (float*)d_out;

  char* ws = (char*)d_ws;
  float* W       = (float*)(ws);                 // 125440 B
  int*   counts  = (int*)  (ws + 125440);        // 160 B
  int*   done    = (int*)  (ws + 125600);        // 32 B
  float* fsm     = (float*)(ws + 125632);        // 40960 B
  float* fmapT   = (float*)(ws + 166592);        // 1605632 B

  hipMemsetAsync(ws, 0, 125632, stream);         // zero W + counts + done
  k_front    <<<2 * NB2 + 400,  256, 0, stream>>>(fmap, fmapT, cam, cls_label,
                                                  hig, low, bg, W, counts);
  k_feat_loss<<<           40, 1024, 0, stream>>>(fmapT, cam, W, counts,
                                                  cls_label, proj_w, fc_init, done, fsm, out);
}

// Round 12
// 132.501 us; speedup vs baseline: 2.9894x; 1.3508x over previous
//
#include <hip/hip_runtime.h>
#include <cstdint>

#define HW 200704      // 448*448
#define IMG_W 448
#define NCLS 20
#define NDIM 256
#define NB2 784        // cam tiles per batch (256 px each)
#define LK 260         // padded LDS stride: float4-aligned

// async global->LDS DMA, 16B per lane, dest = wave-uniform base + lane*16
#define ASYNC_COPY16(gp, lp)                                                   \
  __builtin_amdgcn_global_load_lds(                                            \
      (const __attribute__((address_space(1))) void*)(gp),                     \
      (__attribute__((address_space(3))) void*)(lp), 16, 0, 0)

// ---------------------------------------------------------------------------
// K1: fused [pseudo | transpose]. Pseudo stages only present classes; consume
// is pure top-2; side effects = W atomics ONLY (spread over 31k addresses).
// counts[] atomics eliminated — k_feat derives cnt from sum(W) (==0 exact).
__global__ __launch_bounds__(256) void k_front(const float* __restrict__ fmap,
                                               float* __restrict__ fmapT,
                                               const float* __restrict__ cam,
                                               const float* __restrict__ cls_label,
                                               const float* __restrict__ hig_p,
                                               const float* __restrict__ low_p,
                                               const float* __restrict__ bg_p,
                                               float* __restrict__ W) {
  __shared__ float sT[NCLS][256];      // 20 KB tile (rows 0..np-1 used)
  __shared__ int presList[NCLS];
  __shared__ int sNP;
  int tid = threadIdx.x;

  if (blockIdx.x >= 2 * NB2) {
    // ---------------- transpose part: fmap [B,256,784] -> fmapT [B,784,256]
    float (*tile)[33] = (float (*)[33]) & sT[0][0];
    int blk = blockIdx.x - 2 * NB2;
    int b = blk / 200;
    int t = blk % 200;
    int dT = t / 25, sT2 = t % 25;
    int ty = tid >> 5, tx = tid & 31;
#pragma unroll
    for (int r = 0; r < 4; ++r) {
      int d = dT * 32 + ty + r * 8;
      int s = sT2 * 32 + tx;
      if (s < 784) tile[ty + r * 8][tx] = fmap[((size_t)(b * 256 + d)) * 784 + s];
    }
    __syncthreads();
#pragma unroll
    for (int r = 0; r < 4; ++r) {
      int s = sT2 * 32 + ty + r * 8;
      int d = dT * 32 + tx;
      if (s < 784) fmapT[((size_t)(b * 784 + s)) * 256 + d] = tile[tx][ty + r * 8];
    }
    return;
  }

  // ---------------- pseudo part
  int b = blockIdx.x / NB2;
  int blkInB = blockIdx.x % NB2;
  int pix0 = blkInB * 256;
  int wave = tid >> 6, lane = tid & 63;

  // present-class list via wave ballot
  if (tid < 64) {
    bool pres = (tid < NCLS) && (cls_label[b * NCLS + tid] != 0.0f);
    unsigned long long pm = __ballot(pres);
    if (pres) presList[(int)__popcll(pm & ((1ull << tid) - 1ull))] = tid;
    if (tid == 0) sNP = (int)__popcll(pm);
  }
  __syncthreads();
  int np = sNP;
  const float* camb = cam + (size_t)b * NCLS * HW + pix0;

  // ---- stage: one 1KB DMA per present class ----
  for (int k = wave; k < np; k += 4)
    ASYNC_COPY16(camb + (size_t)presList[k] * HW + lane * 4, &sT[k][0]);
  __syncthreads();                                  // drains vmcnt before ds_read

  // ---- consume: pure branchless top-2 (1 px/thread) ----
  // ascending presList + strict '>' == lowest-index tie-break among present;
  // absent classes contribute only exact 0s -> folded below (proven r2).
  float top1 = -1.0f, sec = -1.0f;
  int cls1 = 0;
  for (int k = 0; k < np; ++k) {
    float x = sT[k][tid];                           // lab==1 for present
    bool gt = x > top1;
    sec = gt ? top1 : fmaxf(sec, fminf(x, top1));
    cls1 = gt ? presList[k] : cls1;
    top1 = gt ? x : top1;
  }
  if (np < NCLS) sec = fmaxf(sec, 0.0f);            // absent-class fold
  float hig = hig_p[0], low = low_p[0], bg = bg_p[0];
  int pix = pix0 + tid;
  int ps = cls1 + 1;
  if (top1 < hig) ps = 255;
  if (top1 < low) ps = 0;
  if (top1 < bg)  ps = 0;
  if ((top1 - sec < 0.3f) && (top1 > hig)) ps = 255;
  if (ps >= 1 && ps <= NCLS) {
    int cls = ps - 1;
    int y = pix / IMG_W, x = pix % IMG_W;
    float sy = (y + 0.5f) * 0.0625f - 0.5f; sy = fminf(fmaxf(sy, 0.0f), 27.0f);
    float sx = (x + 0.5f) * 0.0625f - 0.5f; sx = fminf(fmaxf(sx, 0.0f), 27.0f);
    int fy0 = (int)sy, fx0 = (int)sx;
    int fy1 = min(fy0 + 1, 27), fx1 = min(fx0 + 1, 27);
    float wy = sy - (float)fy0, wx = sx - (float)fx0;
    float* Wb = W + (size_t)(b * NCLS + cls) * 784;
    atomicAdd(&Wb[fy0 * 28 + fx0], (1.0f - wy) * (1.0f - wx));   // spread addrs
    atomicAdd(&Wb[fy0 * 28 + fx1], (1.0f - wy) * wx);
    atomicAdd(&Wb[fy1 * 28 + fx0], wy * (1.0f - wx));
    atomicAdd(&Wb[fy1 * 28 + fx1], wy * wx);
  }
}

// ---------------------------------------------------------------------------
// K2: fused features + loss. cnt derived as sum(W row): ==0 is exact (sum of
// non-negatives), divisor |sumW - count| ~1e-3 -> fsm rel err ~1e-6.
__global__ __launch_bounds__(1024) void k_feat_loss(const float* __restrict__ fmapT,
                                                    const float* __restrict__ cam,
                                                    const float* __restrict__ Wg,
                                                    const float* __restrict__ cls_label,
                                                    const float* __restrict__ proj_w,
                                                    const float* __restrict__ fc_init,
                                                    int* __restrict__ done,
                                                    float* __restrict__ fsm_g,
                                                    float* __restrict__ out) {
  __shared__ float sW[784];
  __shared__ float sPart[4][256];
  __shared__ float wv[16]; __shared__ int wi[16];
  __shared__ float selV; __shared__ int selI;
  __shared__ int sTop[25];
  __shared__ int sLast;
  __shared__ float sRed[16];
  __shared__ float sCntf;
  // loss state
  __shared__ float sFsm[NCLS * LK], sFc[NCLS * LK], sPw[NCLS * LK];
  __shared__ float sMat[NCLS * NCLS], sRow[NCLS], sNormI[NCLS], sNormC[NCLS];
  __shared__ int   sZI[NCLS], sZC[NCLS], sQual[NCLS];
  __shared__ float sPres[2][NCLS];
  __shared__ float sScal[2];

  int bc = blockIdx.x;
  int b = bc / NCLS;
  int tid = threadIdx.x;
  int dim = tid & 255, part = tid >> 8;
  bool present = (cls_label[bc] != 0.0f);
  const float* fT = fmapT + (size_t)b * 784 * 256;
  float res = 0.0f;

  if (present) {
    for (int s = tid; s < 784; s += 1024) sW[s] = Wg[(size_t)bc * 784 + s];
    __syncthreads();
    // block reduction of sum(W row); all terms >= 0 so ==0 test is exact
    {
      float cs = (tid < 784) ? sW[tid] : 0.0f;
      for (int off = 32; off > 0; off >>= 1) cs += __shfl_xor(cs, off, 64);
      if ((tid & 63) == 0) sRed[tid >> 6] = cs;
      __syncthreads();
      if (tid == 0) {
        float s = 0.0f;
        for (int w = 0; w < 16; ++w) s += sRed[w];
        sCntf = s;
      }
      __syncthreads();
    }
    float cntf = sCntf;
    if (cntf > 0.0f) {
      float a0 = 0.0f, a1 = 0.0f, a2 = 0.0f, a3 = 0.0f;
      int s0 = part * 196;
      for (int s = s0; s < s0 + 196; s += 4) {
        a0 += sW[s]     * fT[(size_t)(s)     * 256 + dim];
        a1 += sW[s + 1] * fT[(size_t)(s + 1) * 256 + dim];
        a2 += sW[s + 2] * fT[(size_t)(s + 2) * 256 + dim];
        a3 += sW[s + 3] * fT[(size_t)(s + 3) * 256 + dim];
      }
      sPart[part][dim] = (a0 + a1) + (a2 + a3);
      __syncthreads();
      if (tid < 256)
        res = ((sPart[0][tid] + sPart[1][tid]) + (sPart[2][tid] + sPart[3][tid]))
              / fmaxf(cntf, 1.0f);
    } else {
      // ---- exact top-25 (JAX tie-break) by full scan; ~never taken ----
      const float* camc = cam + (size_t)bc * HW;   // lab==1 -> valid_cam == cam
      float lastV = 3.0e38f; int lastI = -1;
      for (int r = 0; r < 25; ++r) {
        float bv = -1.0e30f; int bi = 0x7fffffff;
        for (int p = tid; p < HW; p += 1024) {
          float vv2 = camc[p];
          if (((vv2 < lastV) || (vv2 == lastV && p > lastI)) &&
              ((vv2 > bv) || (vv2 == bv && p < bi))) { bv = vv2; bi = p; }
        }
        for (int off = 32; off > 0; off >>= 1) {
          float ov = __shfl_xor(bv, off, 64);
          int   oi = __shfl_xor(bi, off, 64);
          if (ov > bv || (ov == bv && oi < bi)) { bv = ov; bi = oi; }
        }
        if ((tid & 63) == 0) { wv[tid >> 6] = bv; wi[tid >> 6] = bi; }
        __syncthreads();
        if (tid == 0) {
          for (int w = 1; w < 16; ++w)
            if (wv[w] > bv || (wv[w] == bv && wi[w] < bi)) { bv = wv[w]; bi = wi[w]; }
          selV = bv; selI = bi; sTop[r] = bi;
        }
        __syncthreads();
        lastV = selV; lastI = selI;
      }
      float at = 0.0f;
      for (int r = part; r < 25; r += 4) {
        int p = sTop[r];
        int y = p / IMG_W, x = p % IMG_W;
        float sy = (y + 0.5f) * 0.0625f - 0.5f; sy = fminf(fmaxf(sy, 0.0f), 27.0f);
        float sx = (x + 0.5f) * 0.0625f - 0.5f; sx = fminf(fmaxf(sx, 0.0f), 27.0f);
        int fy0 = (int)sy, fx0 = (int)sx;
        int fy1 = min(fy0 + 1, 27), fx1 = min(fx0 + 1, 27);
        float wy = sy - (float)fy0, wx = sx - (float)fx0;
        at += (1.0f - wy) * (1.0f - wx) * fT[(size_t)(fy0 * 28 + fx0) * 256 + dim]
            + (1.0f - wy) * wx          * fT[(size_t)(fy0 * 28 + fx1) * 256 + dim]
            + wy          * (1.0f - wx) * fT[(size_t)(fy1 * 28 + fx0) * 256 + dim]
            + wy          * wx          * fT[(size_t)(fy1 * 28 + fx1) * 256 + dim];
      }
      sPart[part][dim] = at;
      __syncthreads();
      if (tid < 256)
        res = ((sPart[0][tid] + sPart[1][tid]) + (sPart[2][tid] + sPart[3][tid])) * (1.0f / 25.0f);
    }
  }
  if (tid < 256) fsm_g[(size_t)bc * 256 + tid] = res;
  __syncthreads();
  // ---- last-block ticket ----
  if (tid == 0) {
    __threadfence();
    int t = atomicAdd(done, 1);
    sLast = (t == 39) ? 1 : 0;
  }
  __syncthreads();
  if (!sLast) return;
  __threadfence();

  // ================= loss (identical math to r7-r11) =======================
  for (int idx = tid; idx < NCLS * NDIM; idx += 1024) {
    int r = idx >> 8, d = idx & 255;
    sFc[r * LK + d] = fc_init[idx];
    sPw[r * LK + d] = proj_w[idx];
  }
  if (tid < 40) sPres[tid / NCLS][tid % NCLS] = cls_label[tid];
  if (tid == 0) { sScal[0] = 0.0f; sScal[1] = 0.0f; }
  __syncthreads();

  for (int bb = 0; bb < 2; ++bb) {
    for (int idx = tid; idx < NCLS * NDIM; idx += 1024)
      sFsm[(idx >> 8) * LK + (idx & 255)] = fsm_g[bb * NCLS * NDIM + idx];
    __syncthreads();
    {
      int g = tid >> 3, sub = tid & 7;
      if (g < 40) {
        const float* row = (g < NCLS) ? &sFsm[g * LK] : &sFc[(g - NCLS) * LK];
        float a0 = 0.0f, a1 = 0.0f, a2 = 0.0f, a3 = 0.0f;
        int d0 = sub * 32;
#pragma unroll
        for (int d = d0; d < d0 + 32; d += 8) {
          float4 x = *(const float4*)&row[d];
          float4 y = *(const float4*)&row[d + 4];
          a0 += x.x * x.x + x.y * x.y;
          a1 += x.z * x.z + x.w * x.w;
          a2 += y.x * y.x + y.y * y.y;
          a3 += y.z * y.z + y.w * y.w;
        }
        float s = (a0 + a1) + (a2 + a3);
        s += __shfl_xor(s, 1, 64);
        s += __shfl_xor(s, 2, 64);
        s += __shfl_xor(s, 4, 64);
        if (sub == 0) {
          if (g < NCLS) { sNormI[g] = fmaxf(sqrtf(s), 1e-12f); sZI[g] = (s == 0.0f); }
          else { sNormC[g - NCLS] = fmaxf(sqrtf(s), 1e-12f); sZC[g - NCLS] = (s == 0.0f); }
        }
      }
    }
    __syncthreads();
    {
      int pair = tid >> 1, sub = tid & 1;
      if (pair < 400) {
        int i = pair / NCLS, j = pair % NCLS;
        float c0;
        if (sZI[i] || sZC[j]) c0 = 0.0f;
        else {
          const float* ra = &sFsm[i * LK];
          const float* rb = &sFc[j * LK];
          float a0 = 0.0f, a1 = 0.0f, a2 = 0.0f, a3 = 0.0f;
          int d0 = sub * 128;
          for (int d = d0; d < d0 + 128; d += 8) {
            float4 x  = *(const float4*)&ra[d];
            float4 y  = *(const float4*)&rb[d];
            float4 x2 = *(const float4*)&ra[d + 4];
            float4 y2 = *(const float4*)&rb[d + 4];
            a0 += x.x * y.x + x.y * y.y;
            a1 += x.z * y.z + x.w * y.w;
            a2 += x2.x * y2.x + x2.y * y2.y;
            a3 += x2.z * y2.z + x2.w * y2.w;
          }
          float acc = (a0 + a1) + (a2 + a3);
          acc += __shfl_xor(acc, 1, 64);
          c0 = fabsf(acc / (sNormI[i] * sNormC[j]));
        }
        if (sub == 0) sMat[pair] = fminf(fmaxf(c0, 1e-5f), 1.0f - 1e-5f);
      }
    }
    __syncthreads();
    {
      int i = tid >> 5, jj = tid & 31;
      if (i < NCLS) {
        float pres = (sPres[bb][i] > 0.5f) ? 1.0f : 0.0f;
        float contrib = 0.0f, omv = -3.0e38f;
        if (jj < NCLS) {
          float c0 = sMat[i * NCLS + jj];
          float ident = (jj == i) ? pres : 0.0f;
          contrib = ident * logf(c0) + (1.0f - ident) * log1pf(-c0);
          if (jj != i) omv = c0;
        }
#pragma unroll
        for (int off = 1; off < 32; off <<= 1) {
          contrib += __shfl_xor(contrib, off, 64);
          omv = fmaxf(omv, __shfl_xor(omv, off, 64));
        }
        if (jj == 0) { sRow[i] = contrib; sQual[i] = (pres > 0.5f && omv < 0.6f) ? 1 : 0; }
      }
    }
    __syncthreads();
    if (tid == 0) {
      float s = 0.0f;
      for (int r = 0; r < NCLS; ++r) s += sRow[r];
      sScal[0] -= s / 400.0f;
    }
    __syncthreads();
    {
      int pair = tid >> 1, sub = tid & 1;
      if (pair < 400) {
        int i = pair / NCLS, j = pair % NCLS;
        float acc = 0.0f;
        if (!sZI[i]) {
          const float* ra = &sFsm[i * LK];
          const float* rb = &sPw[j * LK];
          float a0 = 0.0f, a1 = 0.0f, a2 = 0.0f, a3 = 0.0f;
          int d0 = sub * 128;
          for (int d = d0; d < d0 + 128; d += 8) {
            float4 x  = *(const float4*)&ra[d];
            float4 y  = *(const float4*)&rb[d];
            float4 x2 = *(const float4*)&ra[d + 4];
            float4 y2 = *(const float4*)&rb[d + 4];
            a0 += x.x * y.x + x.y * y.y;
            a1 += x.z * y.z + x.w * y.w;
            a2 += x2.x * y2.x + x2.y * y2.y;
            a3 += x2.z * y2.z + x2.w * y2.w;
          }
          acc = (a0 + a1) + (a2 + a3);
          acc += __shfl_xor(acc, 1, 64);
        }
        if (sub == 0) sMat[pair] = acc;
      }
    }
    __syncthreads();
    {
      int i = tid >> 5, jj = tid & 31;
      if (i < NCLS) {
        float l = (jj < NCLS) ? sMat[i * NCLS + jj] : -3.0e38f;
        float m = l;
#pragma unroll
        for (int off = 1; off < 32; off <<= 1) m = fmaxf(m, __shfl_xor(m, off, 64));
        float e = (jj < NCLS) ? expf(l - m) : 0.0f;
        float S = e;
#pragma unroll
        for (int off = 1; off < 32; off <<= 1) S += __shfl_xor(S, off, 64);
        float term = 0.0f;
        if (jj < NCLS) {
          float p = e / S;
          term = (jj == i) ? fmaxf(logf(p), -100.0f) : fmaxf(log1pf(-p), -100.0f);
        }
#pragma unroll
        for (int off = 1; off < 32; off <<= 1) term += __shfl_xor(term, off, 64);
        if (jj == 0) sRow[i] = -term / 20.0f;
      }
    }
    __syncthreads();
    if (tid == 0) {
      float add = 0.0f; int nq = 0;
      for (int r = 0; r < NCLS; ++r) if (sQual[r]) { add += sRow[r]; nq++; }
      float lc = sScal[1] + add;
      if (nq > 0) lc = lc / fmaxf((float)nq, 1.0f);
      sScal[1] = lc;
    }
    for (int idx = tid; idx < NCLS * NDIM; idx += 1024) {
      int r = idx >> 8, d = idx & 255;
      if (sQual[r]) sFc[r * LK + d] = 0.95f * sFc[r * LK + d] + 0.05f * sFsm[r * LK + d];
    }
    __syncthreads();
  }
  if (tid == 0) out[0] = sScal[0] + sScal[1];
}

// ---------------------------------------------------------------------------
extern "C" void kernel_launch(void* const* d_in, const int* in_sizes, int n_in,
                              void* d_out, int out_size, void* d_ws, size_t ws_size,
                              hipStream_t stream) {
  const float* fmap      = (const float*)d_in[0];
  const float* cam       = (const float*)d_in[1];
  const float* cls_label = (const float*)d_in[2];
  const float* proj_w    = (const float*)d_in[3];
  const float* fc_init   = (const float*)d_in[4];
  const float* hig       = (const float*)d_in[5];
  const float* low       = (const float*)d_in[6];
  const float* bg        = (const float*)d_in[7];
  float* out = (float*)d_out;

  char* ws = (char*)d_ws;
  float* W       = (float*)(ws);                 // 125440 B
  int*   done    = (int*)  (ws + 125440);        // 32 B
  float* fsm     = (float*)(ws + 125472);        // 40960 B
  float* fmapT   = (float*)(ws + 166432);        // 1605632 B

  hipMemsetAsync(ws, 0, 125472, stream);         // zero W + done
  k_front    <<<2 * NB2 + 400,  256, 0, stream>>>(fmap, fmapT, cam, cls_label,
                                                  hig, low, bg, W);
  k_feat_loss<<<           40, 1024, 0, stream>>>(fmapT, cam, W,
                                                  cls_label, proj_w, fc_init, done, fsm, out);
}

// Round 13
// 128.071 us; speedup vs baseline: 3.0928x; 1.0346x over previous
//
#include <hip/hip_runtime.h>
#include <cstdint>

#define HW 200704      // 448*448
#define IMG_W 448
#define NCLS 20
#define NDIM 256
#define NB2 784        // cam tiles per batch (256 px each)
#define LK 260         // padded LDS stride: float4-aligned

// async global->LDS DMA, 16B per lane, dest = wave-uniform base + lane*16
#define ASYNC_COPY16(gp, lp)                                                   \
  __builtin_amdgcn_global_load_lds(                                            \
      (const __attribute__((address_space(1))) void*)(gp),                     \
      (__attribute__((address_space(3))) void*)(lp), 16, 0, 0)

// ---------------------------------------------------------------------------
// K1: fused [pseudo | transpose] (r12, unchanged — counts-atomic-free).
__global__ __launch_bounds__(256) void k_front(const float* __restrict__ fmap,
                                               float* __restrict__ fmapT,
                                               const float* __restrict__ cam,
                                               const float* __restrict__ cls_label,
                                               const float* __restrict__ hig_p,
                                               const float* __restrict__ low_p,
                                               const float* __restrict__ bg_p,
                                               float* __restrict__ W) {
  __shared__ float sT[NCLS][256];
  __shared__ int presList[NCLS];
  __shared__ int sNP;
  int tid = threadIdx.x;

  if (blockIdx.x >= 2 * NB2) {
    float (*tile)[33] = (float (*)[33]) & sT[0][0];
    int blk = blockIdx.x - 2 * NB2;
    int b = blk / 200;
    int t = blk % 200;
    int dT = t / 25, sT2 = t % 25;
    int ty = tid >> 5, tx = tid & 31;
#pragma unroll
    for (int r = 0; r < 4; ++r) {
      int d = dT * 32 + ty + r * 8;
      int s = sT2 * 32 + tx;
      if (s < 784) tile[ty + r * 8][tx] = fmap[((size_t)(b * 256 + d)) * 784 + s];
    }
    __syncthreads();
#pragma unroll
    for (int r = 0; r < 4; ++r) {
      int s = sT2 * 32 + ty + r * 8;
      int d = dT * 32 + tx;
      if (s < 784) fmapT[((size_t)(b * 784 + s)) * 256 + d] = tile[tx][ty + r * 8];
    }
    return;
  }

  int b = blockIdx.x / NB2;
  int blkInB = blockIdx.x % NB2;
  int pix0 = blkInB * 256;
  int wave = tid >> 6, lane = tid & 63;

  if (tid < 64) {
    bool pres = (tid < NCLS) && (cls_label[b * NCLS + tid] != 0.0f);
    unsigned long long pm = __ballot(pres);
    if (pres) presList[(int)__popcll(pm & ((1ull << tid) - 1ull))] = tid;
    if (tid == 0) sNP = (int)__popcll(pm);
  }
  __syncthreads();
  int np = sNP;
  const float* camb = cam + (size_t)b * NCLS * HW + pix0;

  for (int k = wave; k < np; k += 4)
    ASYNC_COPY16(camb + (size_t)presList[k] * HW + lane * 4, &sT[k][0]);
  __syncthreads();

  float top1 = -1.0f, sec = -1.0f;
  int cls1 = 0;
  for (int k = 0; k < np; ++k) {
    float x = sT[k][tid];
    bool gt = x > top1;
    sec = gt ? top1 : fmaxf(sec, fminf(x, top1));
    cls1 = gt ? presList[k] : cls1;
    top1 = gt ? x : top1;
  }
  if (np < NCLS) sec = fmaxf(sec, 0.0f);
  float hig = hig_p[0], low = low_p[0], bg = bg_p[0];
  int pix = pix0 + tid;
  int ps = cls1 + 1;
  if (top1 < hig) ps = 255;
  if (top1 < low) ps = 0;
  if (top1 < bg)  ps = 0;
  if ((top1 - sec < 0.3f) && (top1 > hig)) ps = 255;
  if (ps >= 1 && ps <= NCLS) {
    int cls = ps - 1;
    int y = pix / IMG_W, x = pix % IMG_W;
    float sy = (y + 0.5f) * 0.0625f - 0.5f; sy = fminf(fmaxf(sy, 0.0f), 27.0f);
    float sx = (x + 0.5f) * 0.0625f - 0.5f; sx = fminf(fmaxf(sx, 0.0f), 27.0f);
    int fy0 = (int)sy, fx0 = (int)sx;
    int fy1 = min(fy0 + 1, 27), fx1 = min(fx0 + 1, 27);
    float wy = sy - (float)fy0, wx = sx - (float)fx0;
    float* Wb = W + (size_t)(b * NCLS + cls) * 784;
    atomicAdd(&Wb[fy0 * 28 + fx0], (1.0f - wy) * (1.0f - wx));
    atomicAdd(&Wb[fy0 * 28 + fx1], (1.0f - wy) * wx);
    atomicAdd(&Wb[fy1 * 28 + fx0], wy * (1.0f - wx));
    atomicAdd(&Wb[fy1 * 28 + fx1], wy * wx);
  }
}

// ---------------------------------------------------------------------------
// K2: features only (r12 minus loss/ticket). cnt = sum(W row), ==0 exact.
__global__ __launch_bounds__(1024) void k_feat(const float* __restrict__ fmapT,
                                               const float* __restrict__ cam,
                                               const float* __restrict__ Wg,
                                               const float* __restrict__ cls_label,
                                               float* __restrict__ fsm_g) {
  __shared__ float sW[784];
  __shared__ float sPart[4][256];
  __shared__ float wv[16]; __shared__ int wi[16];
  __shared__ float selV; __shared__ int selI;
  __shared__ int sTop[25];
  __shared__ float sRed[16];
  __shared__ float sCntf;
  int bc = blockIdx.x;
  int b = bc / NCLS;
  int tid = threadIdx.x;
  int dim = tid & 255, part = tid >> 8;
  bool present = (cls_label[bc] != 0.0f);
  const float* fT = fmapT + (size_t)b * 784 * 256;
  float res = 0.0f;

  if (present) {
    for (int s = tid; s < 784; s += 1024) sW[s] = Wg[(size_t)bc * 784 + s];
    __syncthreads();
    {
      float cs = (tid < 784) ? sW[tid] : 0.0f;
      for (int off = 32; off > 0; off >>= 1) cs += __shfl_xor(cs, off, 64);
      if ((tid & 63) == 0) sRed[tid >> 6] = cs;
      __syncthreads();
      if (tid == 0) {
        float s = 0.0f;
        for (int w = 0; w < 16; ++w) s += sRed[w];
        sCntf = s;
      }
      __syncthreads();
    }
    float cntf = sCntf;
    if (cntf > 0.0f) {
      float a0 = 0.0f, a1 = 0.0f, a2 = 0.0f, a3 = 0.0f;
      int s0 = part * 196;
      for (int s = s0; s < s0 + 196; s += 4) {
        a0 += sW[s]     * fT[(size_t)(s)     * 256 + dim];
        a1 += sW[s + 1] * fT[(size_t)(s + 1) * 256 + dim];
        a2 += sW[s + 2] * fT[(size_t)(s + 2) * 256 + dim];
        a3 += sW[s + 3] * fT[(size_t)(s + 3) * 256 + dim];
      }
      sPart[part][dim] = (a0 + a1) + (a2 + a3);
      __syncthreads();
      if (tid < 256)
        res = ((sPart[0][tid] + sPart[1][tid]) + (sPart[2][tid] + sPart[3][tid]))
              / fmaxf(cntf, 1.0f);
    } else {
      // exact top-25 (JAX tie-break) by full scan; ~never taken
      const float* camc = cam + (size_t)bc * HW;
      float lastV = 3.0e38f; int lastI = -1;
      for (int r = 0; r < 25; ++r) {
        float bv = -1.0e30f; int bi = 0x7fffffff;
        for (int p = tid; p < HW; p += 1024) {
          float vv2 = camc[p];
          if (((vv2 < lastV) || (vv2 == lastV && p > lastI)) &&
              ((vv2 > bv) || (vv2 == bv && p < bi))) { bv = vv2; bi = p; }
        }
        for (int off = 32; off > 0; off >>= 1) {
          float ov = __shfl_xor(bv, off, 64);
          int   oi = __shfl_xor(bi, off, 64);
          if (ov > bv || (ov == bv && oi < bi)) { bv = ov; bi = oi; }
        }
        if ((tid & 63) == 0) { wv[tid >> 6] = bv; wi[tid >> 6] = bi; }
        __syncthreads();
        if (tid == 0) {
          for (int w = 1; w < 16; ++w)
            if (wv[w] > bv || (wv[w] == bv && wi[w] < bi)) { bv = wv[w]; bi = wi[w]; }
          selV = bv; selI = bi; sTop[r] = bi;
        }
        __syncthreads();
        lastV = selV; lastI = selI;
      }
      float at = 0.0f;
      for (int r = part; r < 25; r += 4) {
        int p = sTop[r];
        int y = p / IMG_W, x = p % IMG_W;
        float sy = (y + 0.5f) * 0.0625f - 0.5f; sy = fminf(fmaxf(sy, 0.0f), 27.0f);
        float sx = (x + 0.5f) * 0.0625f - 0.5f; sx = fminf(fmaxf(sx, 0.0f), 27.0f);
        int fy0 = (int)sy, fx0 = (int)sx;
        int fy1 = min(fy0 + 1, 27), fx1 = min(fx0 + 1, 27);
        float wy = sy - (float)fy0, wx = sx - (float)fx0;
        at += (1.0f - wy) * (1.0f - wx) * fT[(size_t)(fy0 * 28 + fx0) * 256 + dim]
            + (1.0f - wy) * wx          * fT[(size_t)(fy0 * 28 + fx1) * 256 + dim]
            + wy          * (1.0f - wx) * fT[(size_t)(fy1 * 28 + fx0) * 256 + dim]
            + wy          * wx          * fT[(size_t)(fy1 * 28 + fx1) * 256 + dim];
      }
      sPart[part][dim] = at;
      __syncthreads();
      if (tid < 256)
        res = ((sPart[0][tid] + sPart[1][tid]) + (sPart[2][tid] + sPart[3][tid])) * (1.0f / 25.0f);
    }
  }
  if (tid < 256) fsm_g[(size_t)bc * 256 + tid] = res;
}

// ---------------------------------------------------------------------------
// K3: loss, phase-reduced. Prologue (fc-independent, wide): load both fsm,
// logits for both batches (800 lanes), fsm norms (both) + fc_init norms,
// BCE rows (both). Sequential loop keeps only fcnorm(b1)/cos/row/scalar+EMA.
__global__ __launch_bounds__(1024) void k_loss(const float* __restrict__ fsm_g,
                                               const float* __restrict__ cls_label,
                                               const float* __restrict__ proj_w,
                                               const float* __restrict__ fc_init,
                                               float* __restrict__ out) {
  __shared__ float sFsm[2][NCLS * LK];
  __shared__ float sFc[NCLS * LK], sPw[NCLS * LK];
  __shared__ float sLogit[2][400], sCos[400];
  __shared__ float sBCE[2][NCLS], sRow[NCLS];
  __shared__ float sNormI[2][NCLS], sNormC[NCLS];
  __shared__ int   sZI[2][NCLS], sZC[NCLS], sQual[NCLS];
  __shared__ float sPres[2][NCLS];
  __shared__ float sScal[2];
  int tid = threadIdx.x;

  for (int idx = tid; idx < 2 * NCLS * NDIM; idx += 1024) {
    int b = idx / (NCLS * NDIM);
    int rem = idx - b * NCLS * NDIM;
    sFsm[b][(rem >> 8) * LK + (rem & 255)] = fsm_g[idx];
  }
  for (int idx = tid; idx < NCLS * NDIM; idx += 1024) {
    int r = idx >> 8, d = idx & 255;
    sFc[r * LK + d] = fc_init[idx];
    sPw[r * LK + d] = proj_w[idx];
  }
  if (tid < 40) sPres[tid / NCLS][tid % NCLS] = cls_label[tid];
  if (tid == 0) { sScal[0] = 0.0f; sScal[1] = 0.0f; }
  __syncthreads();

  // ---- P1: logits for BOTH batches, 1 lane/pair, 8 accumulators ----
  // (zero fsm row -> dot is exactly 0.0, matching the old skip)
  if (tid < 800) {
    int b = tid / 400, pi = tid % 400;
    int i = pi / NCLS, j = pi % NCLS;
    const float* ra = &sFsm[b][i * LK];
    const float* rb = &sPw[j * LK];
    float a0 = 0, a1 = 0, a2 = 0, a3 = 0, a4 = 0, a5 = 0, a6 = 0, a7 = 0;
    for (int d = 0; d < 256; d += 16) {
      float4 x0 = *(const float4*)&ra[d],      y0 = *(const float4*)&rb[d];
      float4 x1 = *(const float4*)&ra[d + 4],  y1 = *(const float4*)&rb[d + 4];
      float4 x2 = *(const float4*)&ra[d + 8],  y2 = *(const float4*)&rb[d + 8];
      float4 x3 = *(const float4*)&ra[d + 12], y3 = *(const float4*)&rb[d + 12];
      a0 += x0.x * y0.x + x0.y * y0.y;  a1 += x0.z * y0.z + x0.w * y0.w;
      a2 += x1.x * y1.x + x1.y * y1.y;  a3 += x1.z * y1.z + x1.w * y1.w;
      a4 += x2.x * y2.x + x2.y * y2.y;  a5 += x2.z * y2.z + x2.w * y2.w;
      a6 += x3.x * y3.x + x3.y * y3.y;  a7 += x3.z * y3.z + x3.w * y3.w;
    }
    sLogit[b][pi] = ((a0 + a1) + (a2 + a3)) + ((a4 + a5) + (a6 + a7));
  }
  __syncthreads();

  // ---- P2: norms — 40 fsm rows + 20 fc_init rows, 8-lane teams ----
  {
    int g = tid >> 3, sub = tid & 7;
    if (g < 60) {
      const float* row = (g < 40) ? &sFsm[g / NCLS][(g % NCLS) * LK] : &sFc[(g - 40) * LK];
      float a0 = 0.0f, a1 = 0.0f, a2 = 0.0f, a3 = 0.0f;
      int d0 = sub * 32;
#pragma unroll
      for (int d = d0; d < d0 + 32; d += 8) {
        float4 x = *(const float4*)&row[d];
        float4 y = *(const float4*)&row[d + 4];
        a0 += x.x * x.x + x.y * x.y;
        a1 += x.z * x.z + x.w * x.w;
        a2 += y.x * y.x + y.y * y.y;
        a3 += y.z * y.z + y.w * y.w;
      }
      float s = (a0 + a1) + (a2 + a3);
      s += __shfl_xor(s, 1, 64);
      s += __shfl_xor(s, 2, 64);
      s += __shfl_xor(s, 4, 64);
      if (sub == 0) {
        if (g < 40) { sNormI[g / NCLS][g % NCLS] = fmaxf(sqrtf(s), 1e-12f); sZI[g / NCLS][g % NCLS] = (s == 0.0f); }
        else { sNormC[g - 40] = fmaxf(sqrtf(s), 1e-12f); sZC[g - 40] = (s == 0.0f); }
      }
    }
  }
  __syncthreads();

  // ---- P3: BCE rows for BOTH batches (32-lane teams, 2 rounds) ----
  {
    int team = tid >> 5, jj = tid & 31;
    for (int r = team; r < 40; r += 32) {
      int b = r / NCLS, i = r % NCLS;
      float l = (jj < NCLS) ? sLogit[b][i * NCLS + jj] : -3.0e38f;
      float m = l;
#pragma unroll
      for (int off = 1; off < 32; off <<= 1) m = fmaxf(m, __shfl_xor(m, off, 64));
      float e = (jj < NCLS) ? expf(l - m) : 0.0f;
      float S = e;
#pragma unroll
      for (int off = 1; off < 32; off <<= 1) S += __shfl_xor(S, off, 64);
      float term = 0.0f;
      if (jj < NCLS) {
        float p = e / S;
        term = (jj == i) ? fmaxf(logf(p), -100.0f) : fmaxf(log1pf(-p), -100.0f);
      }
#pragma unroll
      for (int off = 1; off < 32; off <<= 1) term += __shfl_xor(term, off, 64);
      if (jj == 0) sBCE[b][i] = -term / 20.0f;
    }
  }
  __syncthreads();

  // ---- sequential over batches: fcnorm(b1) / cos / row+qualify / scalar+EMA
  for (int b = 0; b < 2; ++b) {
    if (b == 1) {
      int g = tid >> 3, sub = tid & 7;
      if (g < NCLS) {
        const float* row = &sFc[g * LK];
        float a0 = 0.0f, a1 = 0.0f, a2 = 0.0f, a3 = 0.0f;
        int d0 = sub * 32;
#pragma unroll
        for (int d = d0; d < d0 + 32; d += 8) {
          float4 x = *(const float4*)&row[d];
          float4 y = *(const float4*)&row[d + 4];
          a0 += x.x * x.x + x.y * x.y;
          a1 += x.z * x.z + x.w * x.w;
          a2 += y.x * y.x + y.y * y.y;
          a3 += y.z * y.z + y.w * y.w;
        }
        float s = (a0 + a1) + (a2 + a3);
        s += __shfl_xor(s, 1, 64);
        s += __shfl_xor(s, 2, 64);
        s += __shfl_xor(s, 4, 64);
        if (sub == 0) { sNormC[g] = fmaxf(sqrtf(s), 1e-12f); sZC[g] = (s == 0.0f); }
      }
      __syncthreads();
    }
    // cos dots (2 lanes/pair); zero-row skip exact
    {
      int pair = tid >> 1, sub = tid & 1;
      if (pair < 400) {
        int i = pair / NCLS, j = pair % NCLS;
        float c0;
        if (sZI[b][i] || sZC[j]) c0 = 0.0f;
        else {
          const float* ra = &sFsm[b][i * LK];
          const float* rb = &sFc[j * LK];
          float a0 = 0.0f, a1 = 0.0f, a2 = 0.0f, a3 = 0.0f;
          int d0 = sub * 128;
          for (int d = d0; d < d0 + 128; d += 8) {
            float4 x  = *(const float4*)&ra[d];
            float4 y  = *(const float4*)&rb[d];
            float4 x2 = *(const float4*)&ra[d + 4];
            float4 y2 = *(const float4*)&rb[d + 4];
            a0 += x.x * y.x + x.y * y.y;
            a1 += x.z * y.z + x.w * y.w;
            a2 += x2.x * y2.x + x2.y * y2.y;
            a3 += x2.z * y2.z + x2.w * y2.w;
          }
          float acc = (a0 + a1) + (a2 + a3);
          acc += __shfl_xor(acc, 1, 64);
          c0 = fabsf(acc / (sNormI[b][i] * sNormC[j]));
        }
        if (sub == 0) sCos[pair] = fminf(fmaxf(c0, 1e-5f), 1.0f - 1e-5f);
      }
    }
    __syncthreads();
    // row loss + qualify
    {
      int i = tid >> 5, jj = tid & 31;
      if (i < NCLS) {
        float pres = (sPres[b][i] > 0.5f) ? 1.0f : 0.0f;
        float contrib = 0.0f, omv = -3.0e38f;
        if (jj < NCLS) {
          float c0 = sCos[i * NCLS + jj];
          float ident = (jj == i) ? pres : 0.0f;
          contrib = ident * logf(c0) + (1.0f - ident) * log1pf(-c0);
          if (jj != i) omv = c0;
        }
#pragma unroll
        for (int off = 1; off < 32; off <<= 1) {
          contrib += __shfl_xor(contrib, off, 64);
          omv = fmaxf(omv, __shfl_xor(omv, off, 64));
        }
        if (jj == 0) { sRow[i] = contrib; sQual[i] = (pres > 0.5f && omv < 0.6f) ? 1 : 0; }
      }
    }
    __syncthreads();
    // scalars + EMA
    if (tid == 0) {
      float s = 0.0f;
      for (int r = 0; r < NCLS; ++r) s += sRow[r];
      sScal[0] -= s / 400.0f;
      float add = 0.0f; int nq = 0;
      for (int r = 0; r < NCLS; ++r) if (sQual[r]) { add += sBCE[b][r]; nq++; }
      float lc = sScal[1] + add;
      if (nq > 0) lc = lc / fmaxf((float)nq, 1.0f);
      sScal[1] = lc;
    }
    for (int idx = tid; idx < NCLS * NDIM; idx += 1024) {
      int r = idx >> 8, d = idx & 255;
      if (sQual[r]) sFc[r * LK + d] = 0.95f * sFc[r * LK + d] + 0.05f * sFsm[b][r * LK + d];
    }
    __syncthreads();
  }
  if (tid == 0) out[0] = sScal[0] + sScal[1];
}

// ---------------------------------------------------------------------------
extern "C" void kernel_launch(void* const* d_in, const int* in_sizes, int n_in,
                              void* d_out, int out_size, void* d_ws, size_t ws_size,
                              hipStream_t stream) {
  const float* fmap      = (const float*)d_in[0];
  const float* cam       = (const float*)d_in[1];
  const float* cls_label = (const float*)d_in[2];
  const float* proj_w    = (const float*)d_in[3];
  const float* fc_init   = (const float*)d_in[4];
  const float* hig       = (const float*)d_in[5];
  const float* low       = (const float*)d_in[6];
  const float* bg        = (const float*)d_in[7];
  float* out = (float*)d_out;

  char* ws = (char*)d_ws;
  float* W       = (float*)(ws);                 // 125440 B
  float* fsm     = (float*)(ws + 125440);        // 40960 B
  float* fmapT   = (float*)(ws + 166400);        // 1605632 B

  hipMemsetAsync(ws, 0, 125440, stream);         // zero W
  k_front<<<2 * NB2 + 400,  256, 0, stream>>>(fmap, fmapT, cam, cls_label,
                                              hig, low, bg, W);
  k_feat <<<           40, 1024, 0, stream>>>(fmapT, cam, W, cls_label, fsm);
  k_loss <<<            1, 1024, 0, stream>>>(fsm, cls_label, proj_w, fc_init, out);
}

// Round 14
// 123.691 us; speedup vs baseline: 3.2024x; 1.0354x over previous
//
#include <hip/hip_runtime.h>
#include <cstdint>

#define HW 200704      // 448*448
#define IMG_W 448
#define NCLS 20
#define NDIM 256
#define NB2 784        // cam tiles per batch (256 px each)
#define LK 260         // padded LDS stride: float4-aligned

// async global->LDS DMA, 4B per lane, dest = wave-uniform base + lane*4
#define ASYNC_COPY4(gp, lp)                                                    \
  __builtin_amdgcn_global_load_lds(                                            \
      (const __attribute__((address_space(1))) void*)(gp),                     \
      (__attribute__((address_space(3))) void*)(lp), 4, 0, 0)

// ---------------------------------------------------------------------------
// K1: fused [pseudo | transpose]. Pseudo is BARRIER-FREE: each wave ballots
// its own present-mask, DMAs its own 64-px column segment of each present
// class row, drains with a per-wave s_waitcnt, consumes its own columns.
__global__ __launch_bounds__(256) void k_front(const float* __restrict__ fmap,
                                               float* __restrict__ fmapT,
                                               const float* __restrict__ cam,
                                               const float* __restrict__ cls_label,
                                               const float* __restrict__ hig_p,
                                               const float* __restrict__ low_p,
                                               const float* __restrict__ bg_p,
                                               float* __restrict__ W) {
  __shared__ float sT[NCLS][256];      // 20 KB; row k = k-th present class
  int tid = threadIdx.x;

  if (blockIdx.x >= 2 * NB2) {
    // ---------------- transpose part: fmap [B,256,784] -> fmapT [B,784,256]
    float (*tile)[33] = (float (*)[33]) & sT[0][0];
    int blk = blockIdx.x - 2 * NB2;
    int b = blk / 200;
    int t = blk % 200;
    int dT = t / 25, sT2 = t % 25;
    int ty = tid >> 5, tx = tid & 31;
#pragma unroll
    for (int r = 0; r < 4; ++r) {
      int d = dT * 32 + ty + r * 8;
      int s = sT2 * 32 + tx;
      if (s < 784) tile[ty + r * 8][tx] = fmap[((size_t)(b * 256 + d)) * 784 + s];
    }
    __syncthreads();
#pragma unroll
    for (int r = 0; r < 4; ++r) {
      int s = sT2 * 32 + ty + r * 8;
      int d = dT * 32 + tx;
      if (s < 784) fmapT[((size_t)(b * 784 + s)) * 256 + d] = tile[tx][ty + r * 8];
    }
    return;
  }

  // ---------------- pseudo part (no __syncthreads anywhere)
  int b = blockIdx.x / NB2;
  int blkInB = blockIdx.x % NB2;
  int pix0 = blkInB * 256;
  int wave = tid >> 6, lane = tid & 63;

  // per-wave present mask (bits 0..19), no LDS, no barrier
  bool pres = (lane < NCLS) && (cls_label[b * NCLS + lane] != 0.0f);
  unsigned long long pm = __ballot(pres);
  unsigned mask = (unsigned)(pm & 0xFFFFFu);
  int np = __popc(mask);
  const float* camb = cam + (size_t)b * NCLS * HW + pix0 + wave * 64 + lane;

  // ---- stage: np fire-and-forget 256B DMAs into own column segment ----
  {
    unsigned m = mask;
    for (int k = 0; k < np; ++k) {
      int c = __builtin_ctz(m); m &= m - 1u;
      ASYNC_COPY4(camb + (size_t)c * HW, &sT[k][wave * 64]);
    }
  }
  __builtin_amdgcn_s_waitcnt(0);       // per-wave drain: vmcnt(0) lgkmcnt(0)

  // ---- consume: branchless top-2 over own pixel (ascending class order) ----
  float top1 = -1.0f, sec = -1.0f;
  int cls1 = 0;
  {
    unsigned m = mask;
    for (int k = 0; k < np; ++k) {
      int c = __builtin_ctz(m); m &= m - 1u;
      float x = sT[k][tid];            // own wave's columns only
      bool gt = x > top1;
      sec = gt ? top1 : fmaxf(sec, fminf(x, top1));
      cls1 = gt ? c : cls1;
      top1 = gt ? x : top1;
    }
  }
  if (np < NCLS) sec = fmaxf(sec, 0.0f);   // absent classes contribute exact 0s
  float hig = hig_p[0], low = low_p[0], bg = bg_p[0];
  int pix = pix0 + tid;
  int ps = cls1 + 1;
  if (top1 < hig) ps = 255;
  if (top1 < low) ps = 0;
  if (top1 < bg)  ps = 0;
  if ((top1 - sec < 0.3f) && (top1 > hig)) ps = 255;
  if (ps >= 1 && ps <= NCLS) {
    int cls = ps - 1;
    int y = pix / IMG_W, x = pix % IMG_W;
    float sy = (y + 0.5f) * 0.0625f - 0.5f; sy = fminf(fmaxf(sy, 0.0f), 27.0f);
    float sx = (x + 0.5f) * 0.0625f - 0.5f; sx = fminf(fmaxf(sx, 0.0f), 27.0f);
    int fy0 = (int)sy, fx0 = (int)sx;
    int fy1 = min(fy0 + 1, 27), fx1 = min(fx0 + 1, 27);
    float wy = sy - (float)fy0, wx = sx - (float)fx0;
    float* Wb = W + (size_t)(b * NCLS + cls) * 784;
    atomicAdd(&Wb[fy0 * 28 + fx0], (1.0f - wy) * (1.0f - wx));
    atomicAdd(&Wb[fy0 * 28 + fx1], (1.0f - wy) * wx);
    atomicAdd(&Wb[fy1 * 28 + fx0], wy * (1.0f - wx));
    atomicAdd(&Wb[fy1 * 28 + fx1], wy * wx);
  }
}

// ---------------------------------------------------------------------------
// K2: features, split-K across blocks. grid = 40*4, block 512 (dim=tid&255,
// h=tid>>8 computes {a0,a1} or {a2,a3} -> same summation tree as r13).
// Partials P[bc][part][dim]; combine happens in k_loss.
__global__ __launch_bounds__(512) void k_feat(const float* __restrict__ fmapT,
                                              const float* __restrict__ cam,
                                              const float* __restrict__ Wg,
                                              const float* __restrict__ cls_label,
                                              float* __restrict__ P,
                                              float* __restrict__ S,
                                              float* __restrict__ cntW) {
  __shared__ float sW[784];
  __shared__ float sH[2][256];
  __shared__ float sRed[8];
  __shared__ float sCntf;
  __shared__ float wv[8]; __shared__ int wi[8];
  __shared__ float selV; __shared__ int selI;
  __shared__ int sTop[25];
  int bc = blockIdx.x >> 2, part = blockIdx.x & 3;
  int b = bc / NCLS;
  int tid = threadIdx.x;
  int dim = tid & 255, h = tid >> 8;
  if (cls_label[bc] == 0.0f) return;     // combine writes 0 for absent rows

  for (int s = tid; s < 784; s += 512) sW[s] = Wg[(size_t)bc * 784 + s];
  __syncthreads();
  // cnt = sum(W row); non-negative terms -> ==0 test exact
  {
    float cs = sW[tid >= 512 ? 0 : tid];               // guarded below
    cs = (tid < 512) ? sW[tid] : 0.0f;
    if (tid < 272) cs += sW[tid + 512];
    for (int off = 32; off > 0; off >>= 1) cs += __shfl_xor(cs, off, 64);
    if ((tid & 63) == 0) sRed[tid >> 6] = cs;
    __syncthreads();
    if (tid == 0) {
      float s = 0.0f;
      for (int w = 0; w < 8; ++w) s += sRed[w];
      sCntf = s;
    }
    __syncthreads();
  }
  float cntf = sCntf;
  const float* fT = fmapT + (size_t)b * 784 * 256;

  if (cntf > 0.0f) {
    int s0 = part * 196;
    if (h == 0) {
      float a0 = 0.0f, a1 = 0.0f;
      for (int s = s0; s < s0 + 196; s += 4) {
        a0 += sW[s]     * fT[(size_t)(s)     * 256 + dim];
        a1 += sW[s + 1] * fT[(size_t)(s + 1) * 256 + dim];
      }
      sH[0][dim] = a0 + a1;
    } else {
      float a2 = 0.0f, a3 = 0.0f;
      for (int s = s0; s < s0 + 196; s += 4) {
        a2 += sW[s + 2] * fT[(size_t)(s + 2) * 256 + dim];
        a3 += sW[s + 3] * fT[(size_t)(s + 3) * 256 + dim];
      }
      sH[1][dim] = a2 + a3;
    }
    __syncthreads();
    if (tid < 256)
      P[(size_t)(bc * 4 + part) * 256 + tid] = sH[0][tid] + sH[1][tid];
    if (part == 0 && tid == 0) cntW[bc] = cntf;
  } else if (part == 0) {
    // exact top-25 (JAX tie-break) by full scan; statistically never taken
    if (tid == 0) cntW[bc] = 0.0f;
    const float* camc = cam + (size_t)bc * HW;
    float lastV = 3.0e38f; int lastI = -1;
    for (int r = 0; r < 25; ++r) {
      float bv = -1.0e30f; int bi = 0x7fffffff;
      for (int p = tid; p < HW; p += 512) {
        float vv2 = camc[p];
        if (((vv2 < lastV) || (vv2 == lastV && p > lastI)) &&
            ((vv2 > bv) || (vv2 == bv && p < bi))) { bv = vv2; bi = p; }
      }
      for (int off = 32; off > 0; off >>= 1) {
        float ov = __shfl_xor(bv, off, 64);
        int   oi = __shfl_xor(bi, off, 64);
        if (ov > bv || (ov == bv && oi < bi)) { bv = ov; bi = oi; }
      }
      if ((tid & 63) == 0) { wv[tid >> 6] = bv; wi[tid >> 6] = bi; }
      __syncthreads();
      if (tid == 0) {
        for (int w = 1; w < 8; ++w)
          if (wv[w] > bv || (wv[w] == bv && wi[w] < bi)) { bv = wv[w]; bi = wi[w]; }
        selV = bv; selI = bi; sTop[r] = bi;
      }
      __syncthreads();
      lastV = selV; lastI = selI;
    }
    if (tid < 256) {
      float at = 0.0f;
      for (int r = 0; r < 25; ++r) {
        int p = sTop[r];
        int y = p / IMG_W, x = p % IMG_W;
        float sy = (y + 0.5f) * 0.0625f - 0.5f; sy = fminf(fmaxf(sy, 0.0f), 27.0f);
        float sx = (x + 0.5f) * 0.0625f - 0.5f; sx = fminf(fmaxf(sx, 0.0f), 27.0f);
        int fy0 = (int)sy, fx0 = (int)sx;
        int fy1 = min(fy0 + 1, 27), fx1 = min(fx0 + 1, 27);
        float wy = sy - (float)fy0, wx = sx - (float)fx0;
        at += (1.0f - wy) * (1.0f - wx) * fT[(size_t)(fy0 * 28 + fx0) * 256 + tid]
            + (1.0f - wy) * wx          * fT[(size_t)(fy0 * 28 + fx1) * 256 + tid]
            + wy          * (1.0f - wx) * fT[(size_t)(fy1 * 28 + fx0) * 256 + tid]
            + wy          * wx          * fT[(size_t)(fy1 * 28 + fx1) * 256 + tid];
      }
      S[(size_t)bc * 256 + tid] = at * (1.0f / 25.0f);
    }
  }
}

// ---------------------------------------------------------------------------
// K3: loss (r13 phase-reduced structure). Prologue combines k_feat partials
// directly into LDS: fsm = ((P0+P1)+(P2+P3))/max(cnt,1) — identical tree.
__global__ __launch_bounds__(1024) void k_loss(const float* __restrict__ P,
                                               const float* __restrict__ S,
                                               const float* __restrict__ cntW,
                                               const float* __restrict__ cls_label,
                                               const float* __restrict__ proj_w,
                                               const float* __restrict__ fc_init,
                                               float* __restrict__ out) {
  __shared__ float sFsm[2][NCLS * LK];
  __shared__ float sFc[NCLS * LK], sPw[NCLS * LK];
  __shared__ float sLogit[2][400], sCos[400];
  __shared__ float sBCE[2][NCLS], sRow[NCLS];
  __shared__ float sNormI[2][NCLS], sNormC[NCLS];
  __shared__ int   sZI[2][NCLS], sZC[NCLS], sQual[NCLS];
  __shared__ float sPres[2][NCLS];
  __shared__ float sScal[2];
  int tid = threadIdx.x;

  // combine partials -> sFsm (both batches)
  for (int idx = tid; idx < 2 * NCLS * NDIM; idx += 1024) {
    int bc = idx >> 8, d = idx & 255;
    float v = 0.0f;
    if (cls_label[bc] != 0.0f) {
      float c = cntW[bc];
      if (c > 0.0f) {
        const float* p = P + (size_t)bc * 1024 + d;
        v = ((p[0] + p[256]) + (p[512] + p[768])) / fmaxf(c, 1.0f);
      } else {
        v = S[(size_t)bc * 256 + d];
      }
    }
    sFsm[bc / NCLS][(bc % NCLS) * LK + d] = v;
  }
  for (int idx = tid; idx < NCLS * NDIM; idx += 1024) {
    int r = idx >> 8, d = idx & 255;
    sFc[r * LK + d] = fc_init[idx];
    sPw[r * LK + d] = proj_w[idx];
  }
  if (tid < 40) sPres[tid / NCLS][tid % NCLS] = cls_label[tid];
  if (tid == 0) { sScal[0] = 0.0f; sScal[1] = 0.0f; }
  __syncthreads();

  // ---- P1: logits for BOTH batches (zero fsm row -> exact 0 dot) ----
  if (tid < 800) {
    int b = tid / 400, pi = tid % 400;
    int i = pi / NCLS, j = pi % NCLS;
    const float* ra = &sFsm[b][i * LK];
    const float* rb = &sPw[j * LK];
    float a0 = 0, a1 = 0, a2 = 0, a3 = 0, a4 = 0, a5 = 0, a6 = 0, a7 = 0;
    for (int d = 0; d < 256; d += 16) {
      float4 x0 = *(const float4*)&ra[d],      y0 = *(const float4*)&rb[d];
      float4 x1 = *(const float4*)&ra[d + 4],  y1 = *(const float4*)&rb[d + 4];
      float4 x2 = *(const float4*)&ra[d + 8],  y2 = *(const float4*)&rb[d + 8];
      float4 x3 = *(const float4*)&ra[d + 12], y3 = *(const float4*)&rb[d + 12];
      a0 += x0.x * y0.x + x0.y * y0.y;  a1 += x0.z * y0.z + x0.w * y0.w;
      a2 += x1.x * y1.x + x1.y * y1.y;  a3 += x1.z * y1.z + x1.w * y1.w;
      a4 += x2.x * y2.x + x2.y * y2.y;  a5 += x2.z * y2.z + x2.w * y2.w;
      a6 += x3.x * y3.x + x3.y * y3.y;  a7 += x3.z * y3.z + x3.w * y3.w;
    }
    sLogit[b][pi] = ((a0 + a1) + (a2 + a3)) + ((a4 + a5) + (a6 + a7));
  }
  __syncthreads();

  // ---- P2: norms — 40 fsm rows + 20 fc_init rows ----
  {
    int g = tid >> 3, sub = tid & 7;
    if (g < 60) {
      const float* row = (g < 40) ? &sFsm[g / NCLS][(g % NCLS) * LK] : &sFc[(g - 40) * LK];
      float a0 = 0.0f, a1 = 0.0f, a2 = 0.0f, a3 = 0.0f;
      int d0 = sub * 32;
#pragma unroll
      for (int d = d0; d < d0 + 32; d += 8) {
        float4 x = *(const float4*)&row[d];
        float4 y = *(const float4*)&row[d + 4];
        a0 += x.x * x.x + x.y * x.y;
        a1 += x.z * x.z + x.w * x.w;
        a2 += y.x * y.x + y.y * y.y;
        a3 += y.z * y.z + y.w * y.w;
      }
      float s = (a0 + a1) + (a2 + a3);
      s += __shfl_xor(s, 1, 64);
      s += __shfl_xor(s, 2, 64);
      s += __shfl_xor(s, 4, 64);
      if (sub == 0) {
        if (g < 40) { sNormI[g / NCLS][g % NCLS] = fmaxf(sqrtf(s), 1e-12f); sZI[g / NCLS][g % NCLS] = (s == 0.0f); }
        else { sNormC[g - 40] = fmaxf(sqrtf(s), 1e-12f); sZC[g - 40] = (s == 0.0f); }
      }
    }
  }
  __syncthreads();

  // ---- P3: BCE rows for BOTH batches ----
  {
    int team = tid >> 5, jj = tid & 31;
    for (int r = team; r < 40; r += 32) {
      int b = r / NCLS, i = r % NCLS;
      float l = (jj < NCLS) ? sLogit[b][i * NCLS + jj] : -3.0e38f;
      float m = l;
#pragma unroll
      for (int off = 1; off < 32; off <<= 1) m = fmaxf(m, __shfl_xor(m, off, 64));
      float e = (jj < NCLS) ? expf(l - m) : 0.0f;
      float sS = e;
#pragma unroll
      for (int off = 1; off < 32; off <<= 1) sS += __shfl_xor(sS, off, 64);
      float term = 0.0f;
      if (jj < NCLS) {
        float p = e / sS;
        term = (jj == i) ? fmaxf(logf(p), -100.0f) : fmaxf(log1pf(-p), -100.0f);
      }
#pragma unroll
      for (int off = 1; off < 32; off <<= 1) term += __shfl_xor(term, off, 64);
      if (jj == 0) sBCE[b][i] = -term / 20.0f;
    }
  }
  __syncthreads();

  // ---- sequential over batches ----
  for (int b = 0; b < 2; ++b) {
    if (b == 1) {
      int g = tid >> 3, sub = tid & 7;
      if (g < NCLS) {
        const float* row = &sFc[g * LK];
        float a0 = 0.0f, a1 = 0.0f, a2 = 0.0f, a3 = 0.0f;
        int d0 = sub * 32;
#pragma unroll
        for (int d = d0; d < d0 + 32; d += 8) {
          float4 x = *(const float4*)&row[d];
          float4 y = *(const float4*)&row[d + 4];
          a0 += x.x * x.x + x.y * x.y;
          a1 += x.z * x.z + x.w * x.w;
          a2 += y.x * y.x + y.y * y.y;
          a3 += y.z * y.z + y.w * y.w;
        }
        float s = (a0 + a1) + (a2 + a3);
        s += __shfl_xor(s, 1, 64);
        s += __shfl_xor(s, 2, 64);
        s += __shfl_xor(s, 4, 64);
        if (sub == 0) { sNormC[g] = fmaxf(sqrtf(s), 1e-12f); sZC[g] = (s == 0.0f); }
      }
      __syncthreads();
    }
    {
      int pair = tid >> 1, sub = tid & 1;
      if (pair < 400) {
        int i = pair / NCLS, j = pair % NCLS;
        float c0;
        if (sZI[b][i] || sZC[j]) c0 = 0.0f;
        else {
          const float* ra = &sFsm[b][i * LK];
          const float* rb = &sFc[j * LK];
          float a0 = 0.0f, a1 = 0.0f, a2 = 0.0f, a3 = 0.0f;
          int d0 = sub * 128;
          for (int d = d0; d < d0 + 128; d += 8) {
            float4 x  = *(const float4*)&ra[d];
            float4 y  = *(const float4*)&rb[d];
            float4 x2 = *(const float4*)&ra[d + 4];
            float4 y2 = *(const float4*)&rb[d + 4];
            a0 += x.x * y.x + x.y * y.y;
            a1 += x.z * y.z + x.w * y.w;
            a2 += x2.x * y2.x + x2.y * y2.y;
            a3 += x2.z * y2.z + x2.w * y2.w;
          }
          float acc = (a0 + a1) + (a2 + a3);
          acc += __shfl_xor(acc, 1, 64);
          c0 = fabsf(acc / (sNormI[b][i] * sNormC[j]));
        }
        if (sub == 0) sCos[pair] = fminf(fmaxf(c0, 1e-5f), 1.0f - 1e-5f);
      }
    }
    __syncthreads();
    {
      int i = tid >> 5, jj = tid & 31;
      if (i < NCLS) {
        float pres = (sPres[b][i] > 0.5f) ? 1.0f : 0.0f;
        float contrib = 0.0f, omv = -3.0e38f;
        if (jj < NCLS) {
          float c0 = sCos[i * NCLS + jj];
          float ident = (jj == i) ? pres : 0.0f;
          contrib = ident * logf(c0) + (1.0f - ident) * log1pf(-c0);
          if (jj != i) omv = c0;
        }
#pragma unroll
        for (int off = 1; off < 32; off <<= 1) {
          contrib += __shfl_xor(contrib, off, 64);
          omv = fmaxf(omv, __shfl_xor(omv, off, 64));
        }
        if (jj == 0) { sRow[i] = contrib; sQual[i] = (pres > 0.5f && omv < 0.6f) ? 1 : 0; }
      }
    }
    __syncthreads();
    if (tid == 0) {
      float s = 0.0f;
      for (int r = 0; r < NCLS; ++r) s += sRow[r];
      sScal[0] -= s / 400.0f;
      float add = 0.0f; int nq = 0;
      for (int r = 0; r < NCLS; ++r) if (sQual[r]) { add += sBCE[b][r]; nq++; }
      float lc = sScal[1] + add;
      if (nq > 0) lc = lc / fmaxf((float)nq, 1.0f);
      sScal[1] = lc;
    }
    for (int idx = tid; idx < NCLS * NDIM; idx += 1024) {
      int r = idx >> 8, d = idx & 255;
      if (sQual[r]) sFc[r * LK + d] = 0.95f * sFc[r * LK + d] + 0.05f * sFsm[b][r * LK + d];
    }
    __syncthreads();
  }
  if (tid == 0) out[0] = sScal[0] + sScal[1];
}

// ---------------------------------------------------------------------------
extern "C" void kernel_launch(void* const* d_in, const int* in_sizes, int n_in,
                              void* d_out, int out_size, void* d_ws, size_t ws_size,
                              hipStream_t stream) {
  const float* fmap      = (const float*)d_in[0];
  const float* cam       = (const float*)d_in[1];
  const float* cls_label = (const float*)d_in[2];
  const float* proj_w    = (const float*)d_in[3];
  const float* fc_init   = (const float*)d_in[4];
  const float* hig       = (const float*)d_in[5];
  const float* low       = (const float*)d_in[6];
  const float* bg        = (const float*)d_in[7];
  float* out = (float*)d_out;

  char* ws = (char*)d_ws;
  float* W     = (float*)(ws);                 // 125440 B
  float* cntW  = (float*)(ws + 125440);        // 160 B
  float* P     = (float*)(ws + 125600);        // 40*4*256*4 = 163840 B
  float* S     = (float*)(ws + 289440);        // 40*256*4   = 40960 B
  float* fmapT = (float*)(ws + 330400);        // 1605632 B

  hipMemsetAsync(ws, 0, 125440, stream);       // zero W only
  k_front<<<2 * NB2 + 400,  256, 0, stream>>>(fmap, fmapT, cam, cls_label,
                                              hig, low, bg, W);
  k_feat <<<          160,  512, 0, stream>>>(fmapT, cam, W, cls_label, P, S, cntW);
  k_loss <<<            1, 1024, 0, stream>>>(P, S, cntW, cls_label, proj_w, fc_init, out);
}